// Round 7
// baseline (2818.203 us; speedup 1.0000x reference)
//
#include <hip/hip_runtime.h>
#include <hip/hip_bf16.h>

// TreeLSTM forward, round 7:
// - deterministic across graph replays: MODE 7 zero-fills the VT K-pad (the only
//   previously-uninitialized read); no other state crosses launches.
// - exact fp32 weights: B operand staged from fp32 inputs with on-the-fly hi/lo
//   bf16 split (extra MFMA stream) on every weight GEMM; mergedcvt deleted.
// Topology: 16 perfect ternary trees, depth 6; off[l] l=0..5: {5808,5760,5616,5184,3888,0}.

namespace {

constexpr int NN = 5824;
constexpr int ED = 352;

typedef __bf16 bf16;
typedef short s16x8 __attribute__((ext_vector_type(8)));
typedef float f32x4 __attribute__((ext_vector_type(4)));

__device__ __forceinline__ float sigmoidf_(float x) { return 1.f / (1.f + expf(-x)); }

__device__ __forceinline__ void gload_lds16(const void* g, void* s) {
  __builtin_amdgcn_global_load_lds(
      (const __attribute__((address_space(1))) unsigned int*)g,
      (__attribute__((address_space(3))) unsigned int*)s, 16, 0, 0);
}

// ---------------- bf16 MFMA GEMM ----------------
// C = alpha * (A_hi [+ A_lo]) @ B^T + bias [+Cacc] [relu]
// BSRC 0: B bf16 [N,K].  BSRC 1: B fp32 [N,K], split hi/lo in staging (extra MFMA).
// BSRC 2: B fp32 3-region concat (decoder rows: 5000|300|1024), split hi/lo.
// MODE 0: f32 out, single A        (WXa/IOUa/attO with BSRC1; scores with BSRC0)
// MODE 1: f32 out, dual A          (U_f, ff2)
// MODE 3: bf16 out, single A       (PV, BSRC0)
// MODE 4: pair out + relu, dual A  (ff1)
// MODE 5: f32 out + accum + bias, dual A (U_iou in-place)
// MODE 6: decoder region-select out + 3-way bias, dual A
// MODE 7: bf16 out + VT scatter (incl. K-pad zero fill), dual A (qkv)
template <int MODE, int BSRC>
__global__ __launch_bounds__(256) void bgemm_k(
    const bf16* __restrict__ A, const bf16* __restrict__ Alo,
    const bf16* __restrict__ Bb, const float* __restrict__ Bf,
    const float* __restrict__ Bf0, const float* __restrict__ Bf1,
    const float* __restrict__ Bf2,
    void* __restrict__ Cp, bf16* __restrict__ Clo, const float* __restrict__ Cacc,
    const float* __restrict__ bias, const float* __restrict__ bias1,
    const float* __restrict__ bias2, bf16* __restrict__ VTout, int mpad,
    int M, int N, int K, int lda, int ldb, int ldc, float alpha,
    long long sA1, long long sA2, long long sB1, long long sB2,
    long long sC1, long long sC2, int nh) {
  constexpr bool DUAL = (MODE == 1 || MODE == 4 || MODE == 5 || MODE == 6 || MODE == 7);
  constexpr bool WF = (BSRC >= 1);
  const int bz = blockIdx.z;
  const int b1 = bz / nh, b2 = bz - b1 * nh;
  A += (long long)b1 * sA1 + (long long)b2 * sA2;
  if (DUAL) Alo += (long long)b1 * sA1 + (long long)b2 * sA2;
  if (BSRC == 0) Bb += (long long)b1 * sB1 + (long long)b2 * sB2;
  const long long coff = (long long)b1 * sC1 + (long long)b2 * sC2;
  const int bm = blockIdx.y * 128, bn = blockIdx.x * 128;
  __shared__ bf16 As[128 * 32];
  __shared__ bf16 Ls[DUAL ? 128 * 32 : 8];
  __shared__ bf16 Bh[128 * 32];
  __shared__ bf16 Bl[WF ? 128 * 32 : 8];
  const int tid = threadIdx.x;
  const int l = tid & 63;
  const int wr = ((tid >> 7) & 1) * 64;
  const int wc = ((tid >> 6) & 1) * 64;
  f32x4 acc[4][4];
#pragma unroll
  for (int i = 0; i < 4; ++i)
#pragma unroll
    for (int j = 0; j < 4; ++j) acc[i][j] = (f32x4){0.f, 0.f, 0.f, 0.f};

  for (int k0 = 0; k0 < K; k0 += 32) {
#pragma unroll
    for (int r = 0; r < 2; ++r) {
      int idx = r * 256 + tid;
      int row = idx >> 2, cs = idx & 3;
      int cg = cs ^ (row & 3);
      int ra = bm + row; if (ra > M - 1) ra = M - 1;
      int rb = bn + row; if (rb > N - 1) rb = N - 1;
      gload_lds16(A + (long long)ra * lda + k0 + cg * 8, As + idx * 8);
      if (DUAL) gload_lds16(Alo + (long long)ra * lda + k0 + cg * 8, Ls + idx * 8);
      if (BSRC == 0) {
        gload_lds16(Bb + (long long)rb * ldb + k0 + cg * 8, Bh + idx * 8);
      } else {
        const float* src;
        if (BSRC == 2) {
          if (rb < 5000)      src = Bf0 + (long long)rb * ldb + k0 + cg * 8;
          else if (rb < 5300) src = Bf1 + (long long)(rb - 5000) * ldb + k0 + cg * 8;
          else                src = Bf2 + (long long)(rb - 5300) * ldb + k0 + cg * 8;
        } else {
          src = Bf + (long long)rb * ldb + k0 + cg * 8;
        }
        float4 x = *reinterpret_cast<const float4*>(src);
        float4 y = *reinterpret_cast<const float4*>(src + 4);
        float w[8] = {x.x, x.y, x.z, x.w, y.x, y.y, y.z, y.w};
        bf16 hb_[8], lb_[8];
#pragma unroll
        for (int q = 0; q < 8; ++q) {
          bf16 hq = (bf16)w[q];
          hb_[q] = hq;
          lb_[q] = (bf16)(w[q] - (float)hq);
        }
        *reinterpret_cast<s16x8*>(Bh + idx * 8) = *reinterpret_cast<s16x8*>(hb_);
        *reinterpret_cast<s16x8*>(Bl + idx * 8) = *reinterpret_cast<s16x8*>(lb_);
      }
    }
    __syncthreads();
    s16x8 af[4], al[4], bh[4], bl2[4];
#pragma unroll
    for (int mi = 0; mi < 4; ++mi) {
      int row = wr + mi * 16 + (l & 15);
      int ch = ((l >> 4) ^ row) & 3;
      af[mi] = *reinterpret_cast<const s16x8*>(As + row * 32 + ch * 8);
      if (DUAL) al[mi] = *reinterpret_cast<const s16x8*>(Ls + row * 32 + ch * 8);
    }
#pragma unroll
    for (int ni = 0; ni < 4; ++ni) {
      int row = wc + ni * 16 + (l & 15);
      int ch = ((l >> 4) ^ row) & 3;
      bh[ni] = *reinterpret_cast<const s16x8*>(Bh + row * 32 + ch * 8);
      if (WF) bl2[ni] = *reinterpret_cast<const s16x8*>(Bl + row * 32 + ch * 8);
    }
#pragma unroll
    for (int mi = 0; mi < 4; ++mi)
#pragma unroll
      for (int ni = 0; ni < 4; ++ni) {
        acc[mi][ni] =
            __builtin_amdgcn_mfma_f32_16x16x32_bf16(af[mi], bh[ni], acc[mi][ni], 0, 0, 0);
        if (WF)
          acc[mi][ni] =
              __builtin_amdgcn_mfma_f32_16x16x32_bf16(af[mi], bl2[ni], acc[mi][ni], 0, 0, 0);
        if (DUAL)
          acc[mi][ni] =
              __builtin_amdgcn_mfma_f32_16x16x32_bf16(al[mi], bh[ni], acc[mi][ni], 0, 0, 0);
      }
    __syncthreads();
  }

  const int lc = l & 15, lr4 = (l >> 4) * 4;
#pragma unroll
  for (int mi = 0; mi < 4; ++mi) {
#pragma unroll
    for (int j = 0; j < 4; ++j) {
      int r = bm + wr + mi * 16 + lr4 + j;
      if (MODE != 7 && r >= M) continue;
#pragma unroll
      for (int ni = 0; ni < 4; ++ni) {
        int c = bn + wc + ni * 16 + lc;
        if (c >= N) continue;
        float v = alpha * acc[mi][ni][j];
        if (MODE == 6) {
          v += (c < 5000) ? bias[c] : (c < 5300) ? bias1[c - 5000] : bias2[c - 5300];
        } else if (bias) {
          v += bias[c];
        }
        long long idx = coff + (long long)r * ldc + c;
        if (MODE == 7) {
          // VT scatter covers k-pad: rows in [M, 3*mpad) write zeros.
          if (c >= 1024 && r < 3 * mpad) {
            bf16 pv = (r < M) ? (bf16)v : (bf16)0.f;
            int r3 = r % 3, s = r / 3;
            int hh = (c - 1024) >> 8, n = (c - 1024) & 255;
            VTout[(long long)((r3 * 2 + hh) * 256 + n) * mpad + s] = pv;
          }
          if (r < M) ((bf16*)Cp)[idx] = (bf16)v;
        } else if (MODE == 5) {
          ((float*)Cp)[idx] = v + Cacc[idx];
        } else if (MODE == 0 || MODE == 1) {
          ((float*)Cp)[idx] = v;
        } else if (MODE == 3) {
          ((bf16*)Cp)[idx] = (bf16)v;
        } else if (MODE == 4) {
          v = fmaxf(v, 0.f);
          bf16 hv = (bf16)v;
          ((bf16*)Cp)[idx] = hv;
          Clo[idx] = (bf16)(v - (float)hv);
        } else {  // MODE 6
          float* o0 = (float*)Cp;
          if (c < 5000)      o0[(long long)r * 5000 + c] = v;
          else if (c < 5300) o0[29120000LL + (long long)r * 300 + (c - 5000)] = v;
          else               o0[30867200LL + (long long)r * 1024 + (c - 5300)] = v;
        }
      }
    }
  }
}

static void bgemm(hipStream_t st, int mode, int bsrc,
                  const bf16* A, const bf16* Alo,
                  const bf16* Bb, const float* Bf,
                  const float* Bf0, const float* Bf1, const float* Bf2,
                  void* Cp, bf16* Clo, const float* Cacc,
                  const float* bias, const float* bias1, const float* bias2,
                  bf16* VTout, int mpad,
                  int M, int N, int K, int lda, int ldb, int ldc, float alpha,
                  int batches = 1, long long sA1 = 0, long long sA2 = 0,
                  long long sB1 = 0, long long sB2 = 0, long long sC1 = 0,
                  long long sC2 = 0, int nh = 1) {
  dim3 g((N + 127) / 128, (M + 127) / 128, batches), b(256);
#define BGL(MD_, BS_)                                                                \
  bgemm_k<MD_, BS_><<<g, b, 0, st>>>(A, Alo, Bb, Bf, Bf0, Bf1, Bf2, Cp, Clo, Cacc,   \
                                     bias, bias1, bias2, VTout, mpad, M, N, K, lda,  \
                                     ldb, ldc, alpha, sA1, sA2, sB1, sB2, sC1, sC2, nh)
  if (bsrc == 0) {
    if (mode == 0) BGL(0, 0);
    else           BGL(3, 0);
  } else if (bsrc == 2) {
    BGL(6, 2);
  } else {
    switch (mode) {
      case 0: BGL(0, 1); break;
      case 1: BGL(1, 1); break;
      case 4: BGL(4, 1); break;
      case 5: BGL(5, 1); break;
      default: BGL(7, 1); break;
    }
  }
#undef BGL
}

// ---------------- embedding gather + concat + time-pos + mask -> bf16 ----------------
__global__ __launch_bounds__(256) void embed_k(
    const int* __restrict__ uid, const int* __restrict__ pid, const int* __restrict__ cid,
    const int* __restrict__ gid, const int* __restrict__ tmid, const int* __restrict__ mask,
    const float* __restrict__ ue, const float* __restrict__ pe, const float* __restrict__ ce,
    const float* __restrict__ ge, const float* __restrict__ tp, bf16* __restrict__ xb) {
  int e = blockIdx.x * 256 + threadIdx.x;
  if (e >= NN * ED) return;
  int n = e / ED, j = e - n * ED;
  int mi = mask[n];
  float fm = (float)mi;
  float v;
  if (j < 128)      v = ue[(long long)(uid[n] * mi) * 128 + j];
  else if (j < 256) v = pe[(long long)(pid[n] * mi) * 128 + (j - 128)];
  else if (j < 288) v = ce[(long long)(cid[n] * mi) * 32 + (j - 256)];
  else              v = ge[(long long)(gid[n] * mi) * 64 + (j - 288)];
  v += 0.5f * tp[(long long)(tmid[n] * mi) * ED + j];
  xb[e] = (bf16)(v * fm);
}

// ---------------- forget gates + c_red (reads children's c directly) ----------------
__global__ __launch_bounds__(256) void fcred_k(
    const float* __restrict__ wxa, const float* __restrict__ ufh,
    const float* __restrict__ bf_, const float* __restrict__ c, float* __restrict__ cred,
    int m, int cbase, int tl, int woff) {
  int e = blockIdx.x * 256 + threadIdx.x;
  if (e >= m * 512) return;
  int r = e >> 9, d = e & 511;
  float w = wxa[(long long)(woff + r) * 512 + d] + bf_[d];
  int t = r / tl, p = r - t * tl;
  long long cb = (long long)(cbase + t * 3 * tl + 3 * p) * 512 + d;
  long long ub = (long long)r * 1536;
  float acc = 0.f;
#pragma unroll
  for (int k = 0; k < 3; ++k) {
    float f = sigmoidf_(w + ufh[ub + k * 512 + d]);
    acc += f * c[cb + (long long)k * 512];
  }
  cred[e] = acc;
}

// ---------------- iou -> (h,c); h pair + scatter into next level's mailbox ----------
__global__ __launch_bounds__(256) void combine_k(
    const float* __restrict__ iou, const float* __restrict__ cred, float* __restrict__ c,
    bf16* __restrict__ hhi, bf16* __restrict__ hlo, int off, int m, int tl3, int tlp,
    bf16* __restrict__ nxthi, bf16* __restrict__ nxtlo) {
  int e = blockIdx.x * 256 + threadIdx.x;
  if (e >= m * 512) return;
  int r = e >> 9, d = e & 511;
  long long b = (long long)r * 1536;
  float iv = iou[b + d], ov = iou[b + 512 + d], uv = iou[b + 1024 + d];
  float cr = cred ? cred[e] : 0.f;
  float cn = sigmoidf_(iv) * tanhf(uv) + cr;
  float hn = sigmoidf_(ov) * tanhf(cn);
  long long o = (long long)(off + r) * 512 + d;
  c[o] = cn;
  bf16 hv = (bf16)hn;
  bf16 lo = (bf16)(hn - (float)hv);
  hhi[o] = hv;
  hlo[o] = lo;
  if (nxthi) {
    int t = r / tl3, q = r - t * tl3;
    int qp = q / 3, slot = q - 3 * qp;
    long long dst = (long long)(t * tlp + qp) * 1536 + slot * 512 + d;
    nxthi[dst] = hv;
    nxtlo[dst] = lo;
  }
}

// ---------------- LayerNorm width 512: LN((ahi+alo) + b)*w + bias -> pair ----------
__global__ __launch_bounds__(256) void ln_k(
    const bf16* __restrict__ ahi, const bf16* __restrict__ alo, const float* __restrict__ b,
    const float* __restrict__ w, const float* __restrict__ bias,
    bf16* __restrict__ ohi, bf16* __restrict__ olo) {
  int r = blockIdx.x, t = threadIdx.x;
  long long base = (long long)r * 512;
  float v0 = (float)ahi[base + t] + (float)alo[base + t] + b[base + t];
  float v1 = (float)ahi[base + 256 + t] + (float)alo[base + 256 + t] + b[base + 256 + t];
  __shared__ float s1[256], s2[256];
  s1[t] = v0 + v1;
  s2[t] = v0 * v0 + v1 * v1;
  __syncthreads();
  for (int s = 128; s > 0; s >>= 1) {
    if (t < s) { s1[t] += s1[t + s]; s2[t] += s2[t + s]; }
    __syncthreads();
  }
  float mu = s1[0] * (1.f / 512.f);
  float var = s2[0] * (1.f / 512.f) - mu * mu;
  float rs = rsqrtf(var + 1e-5f);
  float o0 = (v0 - mu) * rs * w[t] + bias[t];
  float o1 = (v1 - mu) * rs * w[256 + t] + bias[256 + t];
  bf16 h0 = (bf16)o0, h1 = (bf16)o1;
  ohi[base + t] = h0;       olo[base + t] = (bf16)(o0 - (float)h0);
  ohi[base + 256 + t] = h1; olo[base + 256 + t] = (bf16)(o1 - (float)h1);
}

// ---------------- row softmax fp32 -> bf16 padded probs ----------------
__global__ __launch_bounds__(256) void softmax_pb_k(
    const float* __restrict__ sc, bf16* __restrict__ pb, int m, int mpad) {
  long long r = blockIdx.x;
  const float* row = sc + r * m;
  bf16* prow = pb + r * mpad;
  int t = threadIdx.x;
  __shared__ float sh[256];
  float mx = -3.4e38f;
  for (int j = t; j < m; j += 256) mx = fmaxf(mx, row[j]);
  sh[t] = mx;
  __syncthreads();
  for (int s = 128; s > 0; s >>= 1) {
    if (t < s) sh[t] = fmaxf(sh[t], sh[t + s]);
    __syncthreads();
  }
  mx = sh[0];
  __syncthreads();
  float sum = 0.f;
  for (int j = t; j < m; j += 256) sum += expf(row[j] - mx);
  sh[t] = sum;
  __syncthreads();
  for (int s = 128; s > 0; s >>= 1) {
    if (t < s) sh[t] += sh[t + s];
    __syncthreads();
  }
  float inv = 1.f / sh[0];
  for (int j = t; j < mpad; j += 256)
    prow[j] = (j < m) ? (bf16)(expf(row[j] - mx) * inv) : (bf16)0.f;
}

}  // namespace

extern "C" void kernel_launch(void* const* d_in, const int* in_sizes, int n_in,
                              void* d_out, int out_size, void* d_ws, size_t ws_size,
                              hipStream_t stream) {
  const int* uid  = (const int*)d_in[0];
  const int* pid  = (const int*)d_in[1];
  const int* cid  = (const int*)d_in[2];
  const int* gid  = (const int*)d_in[3];
  const int* tmid = (const int*)d_in[4];
  const int* mask = (const int*)d_in[5];
  const float* ue = (const float*)d_in[6];
  const float* pe = (const float*)d_in[7];
  const float* ce = (const float*)d_in[8];
  const float* ge = (const float*)d_in[9];
  const float* tp = (const float*)d_in[10];
  const float* W_iou = (const float*)d_in[11];
  const float* U_iou = (const float*)d_in[12];
  const float* b_iou = (const float*)d_in[13];
  const float* W_f = (const float*)d_in[14];
  const float* U_f = (const float*)d_in[15];
  const float* b_f = (const float*)d_in[16];
  const float* qkv_w = (const float*)d_in[17];
  const float* qkv_b = (const float*)d_in[18];
  const float* out_w = (const float*)d_in[19];
  const float* out_b = (const float*)d_in[20];
  const float* ln1_w = (const float*)d_in[21];
  const float* ln1_b = (const float*)d_in[22];
  const float* ff1_w = (const float*)d_in[23];
  const float* ff1_b = (const float*)d_in[24];
  const float* ff2_w = (const float*)d_in[25];
  const float* ff2_b = (const float*)d_in[26];
  const float* ln2_w = (const float*)d_in[27];
  const float* ln2_b = (const float*)d_in[28];
  const float* dpw = (const float*)d_in[29];
  const float* dpb = (const float*)d_in[30];
  const float* dcw = (const float*)d_in[31];
  const float* dcb = (const float*)d_in[32];
  const float* dgw = (const float*)d_in[33];
  const float* dgb = (const float*)d_in[34];

  // ---- d_ws (23.9MB): H pair bf16, Cc fp32 ----
  float* ws = (float*)d_ws;
  bf16* Hhi = (bf16*)ws;                       // el [0, 2,981,888)
  bf16* Hlo = Hhi + 2981888LL;                 // el [2,981,888, 5,963,776)
  float* Cc = ws + 2981888LL;                  // fl [2,981,888, 5,963,776)

  // ---- d_out regions (fl offsets) ----
  float* ob = (float*)d_out;
  float* IOUa = ob;                            // [0, 8,945,664)
  float* WXa  = ob + 8945664LL;                // [.., 9,936,896)
  float* CRED = ob + 9936896LL;                // [.., 10,600,448)
  bf16* RAhi  = (bf16*)(ob + 10600448LL);      // 1,990,656 el
  bf16* RAlo  = RAhi + 1990656LL;
  bf16* RBhi  = (bf16*)(ob + 12591104LL);
  bf16* RBlo  = RBhi + 1990656LL;
  bf16* Xb    = (bf16*)(ob + 14581760LL);      // 2,050,048 el
  float* TB   = ob + 15606784LL;               // transient
  float* SC   = TB;                            // [0, 10,077,696)
  bf16* ATTOb = (bf16*)TB;                     // aliases SC (time-disjoint)
  float* XB   = TB + 995328LL;
  bf16* XChi  = (bf16*)(TB + 2985984LL);
  bf16* XClo  = (bf16*)(TB + 3981312LL);
  float* PQ   = TB + 10077696LL;               // UFH / QKVb / Pb
  bf16* VT    = (bf16*)(TB + 15178752LL);      // 2,015,232 el; ends fl 31,793,152

  float* UFH = PQ;
  bf16* QKVb = (bf16*)PQ;
  bf16* Pb   = (bf16*)PQ;

  // 1) embeddings
  embed_k<<<(NN * ED + 255) / 256, 256, 0, stream>>>(uid, pid, cid, gid, tmid, mask,
                                                     ue, pe, ce, ge, tp, Xb);

  // 2) hoisted projections (fp32 weights): IOU_all (no bias), WX_all
  bgemm(stream, 0, 1, Xb, nullptr, nullptr, W_iou, nullptr, nullptr, nullptr,
        IOUa, nullptr, nullptr, nullptr, nullptr, nullptr, nullptr, 0,
        NN, 1536, 352, 352, 352, 1536, 1.f);
  bgemm(stream, 0, 1, Xb + 3888LL * ED, nullptr, nullptr, W_f, nullptr, nullptr, nullptr,
        WXa, nullptr, nullptr, nullptr, nullptr, nullptr, nullptr, 0,
        1936, 512, 352, 352, 352, 512, 1.f);

  // 3) leaves: combine + scatter into level-4 mailbox RA
  combine_k<<<(3888 * 512 + 255) / 256, 256, 0, stream>>>(
      IOUa, nullptr, Cc, Hhi, Hlo, 0, 3888, 243, 81, RAhi, RAlo);

  static const int OFFL[6] = {5808, 5760, 5616, 5184, 3888, 0};
  int tl = 81;
  for (int l = 4; l >= 0; --l, tl /= 3) {
    int m = 16 * tl;
    int off = OFFL[l];
    int cbase = OFFL[l + 1];
    int T = 3 * m;
    int mpad = (m + 31) & ~31;

    // forget gates: UFH = h_ch(pair) @ U_f^T
    bgemm(stream, 1, 1, RAhi, RAlo, nullptr, U_f, nullptr, nullptr, nullptr,
          UFH, nullptr, nullptr, nullptr, nullptr, nullptr, nullptr, 0,
          m, 1536, 1536, 1536, 1536, 1536, 1.f);
    fcred_k<<<(m * 512 + 255) / 256, 256, 0, stream>>>(WXa, UFH, b_f, Cc, CRED,
                                                       m, cbase, tl, off - 3888);

    bf16 *curhi = RAhi, *curlo = RAlo, *nxthi = RBhi, *nxtlo = RBlo;
    for (int i = 0; i < 2; ++i) {
      // qkv (+fused V^T scatter with zero-filled K-pad)
      bgemm(stream, 7, 1, curhi, curlo, nullptr, qkv_w + (long long)i * 786432,
            nullptr, nullptr, nullptr, QKVb, nullptr, nullptr,
            qkv_b + i * 1536, nullptr, nullptr, VT, mpad,
            T, 1536, 512, 512, 512, 1536, 1.f);
      // scores = (1/16) Q@K^T (bf16 B)
      bgemm(stream, 0, 0, QKVb, nullptr, QKVb + 512, nullptr, nullptr, nullptr, nullptr,
            SC, nullptr, nullptr, nullptr, nullptr, nullptr, nullptr, 0,
            m, m, 256, 4608, 4608, m, 0.0625f,
            6, 1536, 256, 1536, 256, 2LL * m * m, (long long)m * m, 2);
      softmax_pb_k<<<6 * m, 256, 0, stream>>>(SC, Pb, m, mpad);
      // attn @ V
      bgemm(stream, 3, 0, Pb, nullptr, VT, nullptr, nullptr, nullptr, nullptr,
            ATTOb, nullptr, nullptr, nullptr, nullptr, nullptr, nullptr, 0,
            m, 256, mpad, mpad, mpad, 1536, 1.f,
            6, 2LL * m * mpad, (long long)m * mpad, 2LL * 256 * mpad, 256LL * mpad,
            512, 256, 2);
      bgemm(stream, 0, 1, ATTOb, nullptr, nullptr, out_w + (long long)i * 262144,
            nullptr, nullptr, nullptr, XB, nullptr, nullptr,
            out_b + i * 512, nullptr, nullptr, nullptr, 0,
            T, 512, 512, 512, 512, 512, 1.f);
      ln_k<<<T, 256, 0, stream>>>(curhi, curlo, XB, ln1_w + i * 512, ln1_b + i * 512,
                                  nxthi, nxtlo);
      bgemm(stream, 4, 1, nxthi, nxtlo, nullptr, ff1_w + (long long)i * 262144,
            nullptr, nullptr, nullptr, XChi, XClo, nullptr,
            ff1_b + i * 512, nullptr, nullptr, nullptr, 0,
            T, 512, 512, 512, 512, 512, 1.f);
      bgemm(stream, 1, 1, XChi, XClo, nullptr, ff2_w + (long long)i * 262144,
            nullptr, nullptr, nullptr, XB, nullptr, nullptr,
            ff2_b + i * 512, nullptr, nullptr, nullptr, 0,
            T, 512, 512, 512, 512, 512, 1.f);
      ln_k<<<T, 256, 0, stream>>>(nxthi, nxtlo, XB, ln2_w + i * 512, ln2_b + i * 512,
                                  curhi, curlo);
    }

    // iou: in-place accumulate into IOU_all rows [off, off+m) with b_iou
    bgemm(stream, 5, 1, curhi, curlo, nullptr, U_iou, nullptr, nullptr, nullptr,
          IOUa + (long long)off * 1536, nullptr, IOUa + (long long)off * 1536,
          b_iou, nullptr, nullptr, nullptr, 0,
          m, 1536, 1536, 1536, 1536, 1536, 1.f);
    combine_k<<<(m * 512 + 255) / 256, 256, 0, stream>>>(
        IOUa + (long long)off * 1536, CRED, Cc, Hhi, Hlo, off, m, tl, tl / 3,
        l > 0 ? RAhi : nullptr, l > 0 ? RAlo : nullptr);
  }

  // 4) merged decoders: fp32 weights from 3 sources, region-select write over d_out
  bgemm(stream, 6, 2, Hhi, Hlo, nullptr, nullptr, dpw, dcw, dgw,
        ob, nullptr, nullptr, dpb, dcb, dgb, nullptr, 0,
        NN, 6324, 512, 512, 512, 0, 1.f);
}

// Round 9
// 2666.550 us; speedup vs baseline: 1.0569x; 1.0569x over previous
//
#include <hip/hip_runtime.h>
#include <hip/hip_bf16.h>

// TreeLSTM forward, round 9: round-8 structure with the decoder-weight hazard fixed.
// Decoder hi/lo weights CANNOT live in d_out (the decoder GEMM writes all of d_out
// while reading them -> race -> NaN). They go to d_ws when ws_size permits
// (runtime check), else the decoder streams fp32 weights from d_in with on-the-fly
// hi/lo split (round-7-proven path). All other weights pre-split into d_out pools
// that are dead before the decoder runs.
// Topology: 16 perfect ternary trees, depth 6; off[l] l=0..5: {5808,5760,5616,5184,3888,0}.

namespace {

constexpr int NN = 5824;
constexpr int ED = 352;

typedef __bf16 bf16;
typedef short s16x8 __attribute__((ext_vector_type(8)));
typedef float f32x4 __attribute__((ext_vector_type(4)));

__device__ __forceinline__ float sigmoidf_(float x) { return 1.f / (1.f + expf(-x)); }

__device__ __forceinline__ void gload_lds16(const void* g, void* s) {
  __builtin_amdgcn_global_load_lds(
      (const __attribute__((address_space(1))) unsigned int*)g,
      (__attribute__((address_space(3))) unsigned int*)s, 16, 0, 0);
}

// ---------------- bf16 MFMA GEMM ----------------
// C = alpha * (A_hi [+ A_lo]) @ (B_hi [+ B_lo])^T + bias [+Cacc] [relu]
// MFMA stream order fixed: A_hi*B_hi [+ A_hi*B_lo if BPAIR] [+ A_lo*B_hi if DUAL].
// BF32 (decoder fallback only): B staged from fp32 3-region concat (5000|300|1024
// rows) with in-kernel hi/lo split; BPAIR semantics apply.
// MODE 0: f32 out (+bias if non-null)     (IOUa, WXa, UFH, attO, ff2, scores)
// MODE 3: bf16 out                        (PV)
// MODE 4: pair out + relu + bias          (ff1)
// MODE 5: f32 out + bias + accum          (U_iou in-place)
// MODE 6: decoder region-select + 3-way bias
// MODE 7: bf16 out + bias + VT scatter (incl. K-pad zero fill)   (qkv)
template <int MODE, bool DUAL, bool BPAIR, bool BF32>
__global__ __launch_bounds__(256) void bgemm_k(
    const bf16* __restrict__ A, const bf16* __restrict__ Alo,
    const bf16* __restrict__ Bh_, const bf16* __restrict__ Bl_,
    const float* __restrict__ Bf0, const float* __restrict__ Bf1,
    const float* __restrict__ Bf2,
    void* __restrict__ Cp, bf16* __restrict__ Clo, const float* __restrict__ Cacc,
    const float* __restrict__ bias, const float* __restrict__ bias1,
    const float* __restrict__ bias2, bf16* __restrict__ VTout, int mpad,
    int M, int N, int K, int lda, int ldb, int ldc, float alpha,
    long long sA1, long long sA2, long long sB1, long long sB2,
    long long sC1, long long sC2, int nh) {
  const int bz = blockIdx.z;
  const int b1 = bz / nh, b2 = bz - b1 * nh;
  A += (long long)b1 * sA1 + (long long)b2 * sA2;
  if (DUAL) Alo += (long long)b1 * sA1 + (long long)b2 * sA2;
  if (!BF32) {
    Bh_ += (long long)b1 * sB1 + (long long)b2 * sB2;
    if (BPAIR) Bl_ += (long long)b1 * sB1 + (long long)b2 * sB2;
  }
  const long long coff = (long long)b1 * sC1 + (long long)b2 * sC2;
  const int bm = blockIdx.y * 128, bn = blockIdx.x * 128;
  __shared__ bf16 As[128 * 32];
  __shared__ bf16 Ls[DUAL ? 128 * 32 : 8];
  __shared__ bf16 Bh[128 * 32];
  __shared__ bf16 Bl[BPAIR ? 128 * 32 : 8];
  const int tid = threadIdx.x;
  const int l = tid & 63;
  const int wr = ((tid >> 7) & 1) * 64;
  const int wc = ((tid >> 6) & 1) * 64;
  f32x4 acc[4][4];
#pragma unroll
  for (int i = 0; i < 4; ++i)
#pragma unroll
    for (int j = 0; j < 4; ++j) acc[i][j] = (f32x4){0.f, 0.f, 0.f, 0.f};

  for (int k0 = 0; k0 < K; k0 += 32) {
#pragma unroll
    for (int r = 0; r < 2; ++r) {
      int idx = r * 256 + tid;
      int row = idx >> 2, cs = idx & 3;
      int cg = cs ^ (row & 3);
      int ra = bm + row; if (ra > M - 1) ra = M - 1;
      int rb = bn + row; if (rb > N - 1) rb = N - 1;
      gload_lds16(A + (long long)ra * lda + k0 + cg * 8, As + idx * 8);
      if (DUAL) gload_lds16(Alo + (long long)ra * lda + k0 + cg * 8, Ls + idx * 8);
      if (BF32) {
        const float* src;
        if (rb < 5000)      src = Bf0 + (long long)rb * ldb + k0 + cg * 8;
        else if (rb < 5300) src = Bf1 + (long long)(rb - 5000) * ldb + k0 + cg * 8;
        else                src = Bf2 + (long long)(rb - 5300) * ldb + k0 + cg * 8;
        float4 x = *reinterpret_cast<const float4*>(src);
        float4 y = *reinterpret_cast<const float4*>(src + 4);
        float w[8] = {x.x, x.y, x.z, x.w, y.x, y.y, y.z, y.w};
        bf16 hb_[8], lb_[8];
#pragma unroll
        for (int q = 0; q < 8; ++q) {
          bf16 hq = (bf16)w[q];
          hb_[q] = hq;
          lb_[q] = (bf16)(w[q] - (float)hq);
        }
        *reinterpret_cast<s16x8*>(Bh + idx * 8) = *reinterpret_cast<s16x8*>(hb_);
        *reinterpret_cast<s16x8*>(Bl + idx * 8) = *reinterpret_cast<s16x8*>(lb_);
      } else {
        gload_lds16(Bh_ + (long long)rb * ldb + k0 + cg * 8, Bh + idx * 8);
        if (BPAIR) gload_lds16(Bl_ + (long long)rb * ldb + k0 + cg * 8, Bl + idx * 8);
      }
    }
    __syncthreads();
    s16x8 af[4], al[4], bh[4], bl2[4];
#pragma unroll
    for (int mi = 0; mi < 4; ++mi) {
      int row = wr + mi * 16 + (l & 15);
      int ch = ((l >> 4) ^ row) & 3;
      af[mi] = *reinterpret_cast<const s16x8*>(As + row * 32 + ch * 8);
      if (DUAL) al[mi] = *reinterpret_cast<const s16x8*>(Ls + row * 32 + ch * 8);
    }
#pragma unroll
    for (int ni = 0; ni < 4; ++ni) {
      int row = wc + ni * 16 + (l & 15);
      int ch = ((l >> 4) ^ row) & 3;
      bh[ni] = *reinterpret_cast<const s16x8*>(Bh + row * 32 + ch * 8);
      if (BPAIR) bl2[ni] = *reinterpret_cast<const s16x8*>(Bl + row * 32 + ch * 8);
    }
#pragma unroll
    for (int mi = 0; mi < 4; ++mi)
#pragma unroll
      for (int ni = 0; ni < 4; ++ni) {
        acc[mi][ni] =
            __builtin_amdgcn_mfma_f32_16x16x32_bf16(af[mi], bh[ni], acc[mi][ni], 0, 0, 0);
        if (BPAIR)
          acc[mi][ni] =
              __builtin_amdgcn_mfma_f32_16x16x32_bf16(af[mi], bl2[ni], acc[mi][ni], 0, 0, 0);
        if (DUAL)
          acc[mi][ni] =
              __builtin_amdgcn_mfma_f32_16x16x32_bf16(al[mi], bh[ni], acc[mi][ni], 0, 0, 0);
      }
    __syncthreads();
  }

  const int lc = l & 15, lr4 = (l >> 4) * 4;
#pragma unroll
  for (int mi = 0; mi < 4; ++mi) {
#pragma unroll
    for (int j = 0; j < 4; ++j) {
      int r = bm + wr + mi * 16 + lr4 + j;
      if (MODE != 7 && r >= M) continue;
#pragma unroll
      for (int ni = 0; ni < 4; ++ni) {
        int c = bn + wc + ni * 16 + lc;
        if (c >= N) continue;
        float v = alpha * acc[mi][ni][j];
        if (MODE == 6) {
          v += (c < 5000) ? bias[c] : (c < 5300) ? bias1[c - 5000] : bias2[c - 5300];
        } else if (bias) {
          v += bias[c];
        }
        long long idx = coff + (long long)r * ldc + c;
        if (MODE == 7) {
          if (c >= 1024 && r < 3 * mpad) {
            bf16 pv = (r < M) ? (bf16)v : (bf16)0.f;
            int r3 = r % 3, s = r / 3;
            int hh = (c - 1024) >> 8, n = (c - 1024) & 255;
            VTout[(long long)((r3 * 2 + hh) * 256 + n) * mpad + s] = pv;
          }
          if (r < M) ((bf16*)Cp)[idx] = (bf16)v;
        } else if (MODE == 5) {
          ((float*)Cp)[idx] = v + Cacc[idx];
        } else if (MODE == 0) {
          ((float*)Cp)[idx] = v;
        } else if (MODE == 3) {
          ((bf16*)Cp)[idx] = (bf16)v;
        } else if (MODE == 4) {
          v = fmaxf(v, 0.f);
          bf16 hv = (bf16)v;
          ((bf16*)Cp)[idx] = hv;
          Clo[idx] = (bf16)(v - (float)hv);
        } else {  // MODE 6: decoder region select (poi 5000 | cat 300 | coo 1024)
          float* o0 = (float*)Cp;
          if (c < 5000)      o0[(long long)r * 5000 + c] = v;
          else if (c < 5300) o0[29120000LL + (long long)r * 300 + (c - 5000)] = v;
          else               o0[30867200LL + (long long)r * 1024 + (c - 5300)] = v;
        }
      }
    }
  }
}

static void bgemm(hipStream_t st, int mode, bool dual, bool bpair,
                  const bf16* A, const bf16* Alo, const bf16* Bh, const bf16* Bl,
                  void* Cp, bf16* Clo, const float* Cacc,
                  const float* bias, const float* bias1, const float* bias2,
                  bf16* VTout, int mpad,
                  int M, int N, int K, int lda, int ldb, int ldc, float alpha,
                  int batches = 1, long long sA1 = 0, long long sA2 = 0,
                  long long sB1 = 0, long long sB2 = 0, long long sC1 = 0,
                  long long sC2 = 0, int nh = 1,
                  const float* Bf0 = nullptr, const float* Bf1 = nullptr,
                  const float* Bf2 = nullptr, bool bf32 = false) {
  dim3 g((N + 127) / 128, (M + 127) / 128, batches), b(256);
#define BGL(MD_, DU_, BP_, BFF_)                                                         \
  bgemm_k<MD_, DU_, BP_, BFF_><<<g, b, 0, st>>>(A, Alo, Bh, Bl, Bf0, Bf1, Bf2, Cp, Clo,  \
                                                Cacc, bias, bias1, bias2, VTout, mpad,   \
                                                M, N, K, lda, ldb, ldc, alpha, sA1, sA2, \
                                                sB1, sB2, sC1, sC2, nh)
  if (mode == 0 && !dual && bpair)        BGL(0, false, true, false);
  else if (mode == 0 && dual && bpair)    BGL(0, true, true, false);
  else if (mode == 0 && !dual && !bpair)  BGL(0, false, false, false);
  else if (mode == 3)                     BGL(3, false, false, false);
  else if (mode == 4)                     BGL(4, true, true, false);
  else if (mode == 5)                     BGL(5, true, true, false);
  else if (mode == 6 && !bf32)            BGL(6, true, true, false);
  else if (mode == 6 && bf32)             BGL(6, true, true, true);
  else                                    BGL(7, true, true, false);
#undef BGL
}

// ---------------- fp32 -> (hi, lo) bf16 split, segmented; ptrs computed on host ------
struct SegArgs {
  const float* src[8];
  bf16* hi[8];
  bf16* lo[8];
  int start[9];  // prefix sums in 8-element units; trailing entries = total
};
__global__ __launch_bounds__(256) void split_k(SegArgs a, int total8) {
  for (int i = blockIdx.x * 256 + threadIdx.x; i < total8; i += gridDim.x * 256) {
    int s = 0;
    while (i >= a.start[s + 1]) ++s;
    long long off = (long long)(i - a.start[s]) * 8;
    const float4* p = reinterpret_cast<const float4*>(a.src[s] + off);
    float4 x = p[0], y = p[1];
    float w[8] = {x.x, x.y, x.z, x.w, y.x, y.y, y.z, y.w};
    bf16 hb[8], lb[8];
#pragma unroll
    for (int q = 0; q < 8; ++q) {
      bf16 hq = (bf16)w[q];
      hb[q] = hq;
      lb[q] = (bf16)(w[q] - (float)hq);
    }
    *reinterpret_cast<s16x8*>(a.hi[s] + off) = *reinterpret_cast<s16x8*>(hb);
    *reinterpret_cast<s16x8*>(a.lo[s] + off) = *reinterpret_cast<s16x8*>(lb);
  }
}

// ---------------- embedding gather + concat + time-pos + mask -> bf16 ----------------
__global__ __launch_bounds__(256) void embed_k(
    const int* __restrict__ uid, const int* __restrict__ pid, const int* __restrict__ cid,
    const int* __restrict__ gid, const int* __restrict__ tmid, const int* __restrict__ mask,
    const float* __restrict__ ue, const float* __restrict__ pe, const float* __restrict__ ce,
    const float* __restrict__ ge, const float* __restrict__ tp, bf16* __restrict__ xb) {
  int e = blockIdx.x * 256 + threadIdx.x;
  if (e >= NN * ED) return;
  int n = e / ED, j = e - n * ED;
  int mi = mask[n];
  float fm = (float)mi;
  float v;
  if (j < 128)      v = ue[(long long)(uid[n] * mi) * 128 + j];
  else if (j < 256) v = pe[(long long)(pid[n] * mi) * 128 + (j - 128)];
  else if (j < 288) v = ce[(long long)(cid[n] * mi) * 32 + (j - 256)];
  else              v = ge[(long long)(gid[n] * mi) * 64 + (j - 288)];
  v += 0.5f * tp[(long long)(tmid[n] * mi) * ED + j];
  xb[e] = (bf16)(v * fm);
}

// ---------------- forget gates + c_red (reads children's c directly) ----------------
__global__ __launch_bounds__(256) void fcred_k(
    const float* __restrict__ wxa, const float* __restrict__ ufh,
    const float* __restrict__ bf_, const float* __restrict__ c, float* __restrict__ cred,
    int m, int cbase, int tl, int woff) {
  int e = blockIdx.x * 256 + threadIdx.x;
  if (e >= m * 512) return;
  int r = e >> 9, d = e & 511;
  float w = wxa[(long long)(woff + r) * 512 + d] + bf_[d];
  int t = r / tl, p = r - t * tl;
  long long cb = (long long)(cbase + t * 3 * tl + 3 * p) * 512 + d;
  long long ub = (long long)r * 1536;
  float acc = 0.f;
#pragma unroll
  for (int k = 0; k < 3; ++k) {
    float f = sigmoidf_(w + ufh[ub + k * 512 + d]);
    acc += f * c[cb + (long long)k * 512];
  }
  cred[e] = acc;
}

// ---------------- iou -> (h,c); h pair + scatter into next level's mailbox ----------
__global__ __launch_bounds__(256) void combine_k(
    const float* __restrict__ iou, const float* __restrict__ cred, float* __restrict__ c,
    bf16* __restrict__ hhi, bf16* __restrict__ hlo, int off, int m, int tl3, int tlp,
    bf16* __restrict__ nxthi, bf16* __restrict__ nxtlo) {
  int e = blockIdx.x * 256 + threadIdx.x;
  if (e >= m * 512) return;
  int r = e >> 9, d = e & 511;
  long long b = (long long)r * 1536;
  float iv = iou[b + d], ov = iou[b + 512 + d], uv = iou[b + 1024 + d];
  float cr = cred ? cred[e] : 0.f;
  float cn = sigmoidf_(iv) * tanhf(uv) + cr;
  float hn = sigmoidf_(ov) * tanhf(cn);
  long long o = (long long)(off + r) * 512 + d;
  c[o] = cn;
  bf16 hv = (bf16)hn;
  bf16 lo = (bf16)(hn - (float)hv);
  hhi[o] = hv;
  hlo[o] = lo;
  if (nxthi) {
    int t = r / tl3, q = r - t * tl3;
    int qp = q / 3, slot = q - 3 * qp;
    long long dst = (long long)(t * tlp + qp) * 1536 + slot * 512 + d;
    nxthi[dst] = hv;
    nxtlo[dst] = lo;
  }
}

// ---------------- LayerNorm width 512: LN((ahi+alo) + b)*w + bias -> pair ----------
__global__ __launch_bounds__(256) void ln_k(
    const bf16* __restrict__ ahi, const bf16* __restrict__ alo, const float* __restrict__ b,
    const float* __restrict__ w, const float* __restrict__ bias,
    bf16* __restrict__ ohi, bf16* __restrict__ olo) {
  int r = blockIdx.x, t = threadIdx.x;
  long long base = (long long)r * 512;
  float v0 = (float)ahi[base + t] + (float)alo[base + t] + b[base + t];
  float v1 = (float)ahi[base + 256 + t] + (float)alo[base + 256 + t] + b[base + 256 + t];
  __shared__ float s1[256], s2[256];
  s1[t] = v0 + v1;
  s2[t] = v0 * v0 + v1 * v1;
  __syncthreads();
  for (int s = 128; s > 0; s >>= 1) {
    if (t < s) { s1[t] += s1[t + s]; s2[t] += s2[t + s]; }
    __syncthreads();
  }
  float mu = s1[0] * (1.f / 512.f);
  float var = s2[0] * (1.f / 512.f) - mu * mu;
  float rs = rsqrtf(var + 1e-5f);
  float o0 = (v0 - mu) * rs * w[t] + bias[t];
  float o1 = (v1 - mu) * rs * w[256 + t] + bias[256 + t];
  bf16 h0 = (bf16)o0, h1 = (bf16)o1;
  ohi[base + t] = h0;       olo[base + t] = (bf16)(o0 - (float)h0);
  ohi[base + 256 + t] = h1; olo[base + 256 + t] = (bf16)(o1 - (float)h1);
}

// ---------------- row softmax fp32 -> bf16 probs IN PLACE over SC ----------------
// Pb row r = (bf16*)sc + r*2m (within row r's own fp32 storage); pads [m,mpad)=0.
__global__ __launch_bounds__(256) void softmax_pb_k(float* __restrict__ sc, int m, int mpad) {
  long long r = blockIdx.x;
  float* row = sc + r * (long long)m;
  bf16* prow = (bf16*)sc + r * (long long)(2 * m);
  int t = threadIdx.x;
  __shared__ float sh[256];
  float mx = -3.4e38f;
  for (int j = t; j < m; j += 256) mx = fmaxf(mx, row[j]);
  sh[t] = mx;
  __syncthreads();
  for (int s = 128; s > 0; s >>= 1) {
    if (t < s) sh[t] = fmaxf(sh[t], sh[t + s]);
    __syncthreads();
  }
  mx = sh[0];
  __syncthreads();
  float ev[6];  // ceil(1296/256) = 6 max
  float sum = 0.f;
  int cnt = 0;
  for (int j = t; j < m; j += 256) {
    float e = expf(row[j] - mx);
    ev[cnt++] = e;
    sum += e;
  }
  sh[t] = sum;
  __syncthreads();
  for (int s = 128; s > 0; s >>= 1) {
    if (t < s) sh[t] += sh[t + s];
    __syncthreads();
  }
  // all reads of row[] completed before the barrier-terminated reduce -> safe to
  // overwrite the same memory as bf16 now.
  float inv = 1.f / sh[0];
  cnt = 0;
  for (int j = t; j < m; j += 256) prow[j] = (bf16)(ev[cnt++] * inv);
  for (int j = m + t; j < mpad; j += 256) prow[j] = (bf16)0.f;
}

}  // namespace

extern "C" void kernel_launch(void* const* d_in, const int* in_sizes, int n_in,
                              void* d_out, int out_size, void* d_ws, size_t ws_size,
                              hipStream_t stream) {
  const int* uid  = (const int*)d_in[0];
  const int* pid  = (const int*)d_in[1];
  const int* cid  = (const int*)d_in[2];
  const int* gid  = (const int*)d_in[3];
  const int* tmid = (const int*)d_in[4];
  const int* mask = (const int*)d_in[5];
  const float* ue = (const float*)d_in[6];
  const float* pe = (const float*)d_in[7];
  const float* ce = (const float*)d_in[8];
  const float* ge = (const float*)d_in[9];
  const float* tp = (const float*)d_in[10];
  const float* b_iou = (const float*)d_in[13];
  const float* b_f = (const float*)d_in[16];
  const float* qkv_b = (const float*)d_in[18];
  const float* out_b = (const float*)d_in[20];
  const float* ln1_w = (const float*)d_in[21];
  const float* ln1_b = (const float*)d_in[22];
  const float* ff1_b = (const float*)d_in[24];
  const float* ff2_b = (const float*)d_in[26];
  const float* ln2_w = (const float*)d_in[27];
  const float* ln2_b = (const float*)d_in[28];
  const float* dpw = (const float*)d_in[29];
  const float* dpb = (const float*)d_in[30];
  const float* dcw = (const float*)d_in[31];
  const float* dcb = (const float*)d_in[32];
  const float* dgw = (const float*)d_in[33];
  const float* dgb = (const float*)d_in[34];

  // ---- d_ws: H pair bf16 [0, 11.9MB), Cc fp32 [11.9, 23.9MB),
  //      decoder hi/lo pools [23.9, 36.8MB) IF ws_size permits ----
  float* ws = (float*)d_ws;
  bf16* Hhi = (bf16*)ws;
  bf16* Hlo = Hhi + 2981888LL;
  float* Cc = ws + 2981888LL;
  bf16* DhiW = (bf16*)(ws + 5963776LL);        // 3,237,888 el
  bf16* DloW = DhiW + 3237888LL;               // ends fl 9,201,664 (36,806,656 B)
  const bool wsfit = ws_size >= 36806656ULL;

  // ---- d_out map (fl offsets) ----
  float* ob = (float*)d_out;
  float* IOUa = ob;                            // [0, 8,945,664)
  float* WXa  = ob + 8945664LL;                // [.., 9,936,896)
  float* CRED = ob + 9936896LL;                // [.., 10,600,448)
  bf16* RAhi  = (bf16*)(ob + 10600448LL);      // 1,990,656 el
  bf16* RAlo  = RAhi + 1990656LL;
  bf16* RBhi  = (bf16*)(ob + 12591104LL);
  bf16* RBlo  = RBhi + 1990656LL;
  bf16* UP    = (bf16*)(ob + 14581760LL);      // U pool: 9,437,184 el
  bf16* TE    = (bf16*)(ob + 19300352LL);      // TE pool: 6,291,456 el
  float* TB   = ob + 22446080LL;               // transient, 14,384,896 fl

  // U pool
  bf16* Uihi = UP;                  // U_iou hi (2,359,296)
  bf16* Uilo = UP + 2359296LL;
  bf16* Ufhi = UP + 4718592LL;      // U_f hi
  bf16* Uflo = UP + 7077888LL;
  // TE pool
  bf16* qkvhi = TE;                 // 1,572,864 (2 layers)
  bf16* qkvlo = TE + 1572864LL;
  bf16* outhi = TE + 3145728LL;     // 524,288
  bf16* outlo = TE + 3670016LL;
  bf16* ff1hi = TE + 4194304LL;
  bf16* ff1lo = TE + 4718592LL;
  bf16* ff2hi = TE + 5242880LL;
  bf16* ff2lo = TE + 5767168LL;

  // TB layout during level loop:
  float* SC   = TB;                            // [0, 10,077,696) fp32; Pb aliased inside
  float* PQ   = TB + 10077696LL;               // [.., 13,063,680): UFH / QKVb / ATTOb
  bf16* VT    = (bf16*)(TB + 13063680LL);      // 2,015,232 el -> ends TB+14,071,296
  // early-phase aliases in TB (dead before SC first written at level-4 scores):
  bf16* Xb    = (bf16*)TB;                     // 2,050,048 el = 1,025,024 fl
  bf16* WP    = (bf16*)(TB + 1025024LL);       // W pool: 1,441,792 el
  bf16* Wihi  = WP;
  bf16* Wilo  = WP + 540672LL;
  bf16* Wfhi  = WP + 1081344LL;
  bf16* Wflo  = WP + 1261568LL;

  float* UFH  = PQ;
  bf16* QKVb  = (bf16*)PQ;
  bf16* ATTOb = (bf16*)PQ;
  float* XB   = TB;                            // fp32, after Pb dead
  bf16* XChi  = (bf16*)(TB + 1990656LL);
  bf16* XClo  = (bf16*)(TB + 2985984LL);

  // 0) split all level-loop weights into hi/lo pools; decoder weights into d_ws
  //    in the same kernel when they fit.
  {
    SegArgs a{};
    const int n8[8] = {294912, 294912, 196608, 65536, 65536, 65536, 67584, 22528};
    a.src[0] = (const float*)d_in[12]; a.hi[0] = Uihi;  a.lo[0] = Uilo;   // U_iou
    a.src[1] = (const float*)d_in[15]; a.hi[1] = Ufhi;  a.lo[1] = Uflo;   // U_f
    a.src[2] = (const float*)d_in[17]; a.hi[2] = qkvhi; a.lo[2] = qkvlo;  // qkv_w
    a.src[3] = (const float*)d_in[19]; a.hi[3] = outhi; a.lo[3] = outlo;  // out_w
    a.src[4] = (const float*)d_in[23]; a.hi[4] = ff1hi; a.lo[4] = ff1lo;  // ff1_w
    a.src[5] = (const float*)d_in[25]; a.hi[5] = ff2hi; a.lo[5] = ff2lo;  // ff2_w
    a.src[6] = (const float*)d_in[11]; a.hi[6] = Wihi;  a.lo[6] = Wilo;   // W_iou
    a.src[7] = (const float*)d_in[14]; a.hi[7] = Wfhi;  a.lo[7] = Wflo;   // W_f
    a.start[0] = 0;
    for (int i = 0; i < 8; ++i) a.start[i + 1] = a.start[i] + n8[i];
    int total8 = a.start[8];
    int blocks = (total8 + 255) / 256; if (blocks > 4096) blocks = 4096;
    split_k<<<blocks, 256, 0, stream>>>(a, total8);
    if (wsfit) {
      SegArgs d{};
      const int dn8[3] = {320000, 19200, 65536};
      d.src[0] = dpw; d.hi[0] = DhiW;             d.lo[0] = DloW;
      d.src[1] = dcw; d.hi[1] = DhiW + 2560000LL; d.lo[1] = DloW + 2560000LL;
      d.src[2] = dgw; d.hi[2] = DhiW + 2713600LL; d.lo[2] = DloW + 2713600LL;
      d.start[0] = 0;
      for (int i = 0; i < 3; ++i) d.start[i + 1] = d.start[i] + dn8[i];
      for (int i = 3; i < 8; ++i) d.start[i + 1] = d.start[3];
      int dt8 = d.start[3];
      int db = (dt8 + 255) / 256; if (db > 4096) db = 4096;
      split_k<<<db, 256, 0, stream>>>(d, dt8);
    }
  }

  // 1) embeddings
  embed_k<<<(NN * ED + 255) / 256, 256, 0, stream>>>(uid, pid, cid, gid, tmid, mask,
                                                     ue, pe, ce, ge, tp, Xb);

  // 2) hoisted projections: IOU_all (no bias), WX_all
  bgemm(stream, 0, false, true, Xb, nullptr, Wihi, Wilo, IOUa, nullptr, nullptr,
        nullptr, nullptr, nullptr, nullptr, 0, NN, 1536, 352, 352, 352, 1536, 1.f);
  bgemm(stream, 0, false, true, Xb + 3888LL * ED, nullptr, Wfhi, Wflo, WXa, nullptr,
        nullptr, nullptr, nullptr, nullptr, nullptr, 0, 1936, 512, 352, 352, 352, 512, 1.f);

  // 3) leaves: combine + scatter into level-4 mailbox RA
  combine_k<<<(3888 * 512 + 255) / 256, 256, 0, stream>>>(
      IOUa, nullptr, Cc, Hhi, Hlo, 0, 3888, 243, 81, RAhi, RAlo);

  static const int OFFL[6] = {5808, 5760, 5616, 5184, 3888, 0};
  int tl = 81;
  for (int l = 4; l >= 0; --l, tl /= 3) {
    int m = 16 * tl;
    int off = OFFL[l];
    int cbase = OFFL[l + 1];
    int T = 3 * m;
    int mpad = (m + 31) & ~31;

    bgemm(stream, 0, true, true, RAhi, RAlo, Ufhi, Uflo, UFH, nullptr, nullptr,
          nullptr, nullptr, nullptr, nullptr, 0, m, 1536, 1536, 1536, 1536, 1536, 1.f);
    fcred_k<<<(m * 512 + 255) / 256, 256, 0, stream>>>(WXa, UFH, b_f, Cc, CRED,
                                                       m, cbase, tl, off - 3888);

    bf16 *curhi = RAhi, *curlo = RAlo, *nxthi = RBhi, *nxtlo = RBlo;
    for (int i = 0; i < 2; ++i) {
      // qkv (+fused V^T scatter with zero-filled K-pad)
      bgemm(stream, 7, true, true, curhi, curlo, qkvhi + (long long)i * 786432,
            qkvlo + (long long)i * 786432, QKVb, nullptr, nullptr,
            qkv_b + i * 1536, nullptr, nullptr, VT, mpad,
            T, 1536, 512, 512, 512, 1536, 1.f);
      // scores = (1/16) Q@K^T
      bgemm(stream, 0, false, false, QKVb, nullptr, QKVb + 512, nullptr, SC, nullptr,
            nullptr, nullptr, nullptr, nullptr, nullptr, 0,
            m, m, 256, 4608, 4608, m, 0.0625f,
            6, 1536, 256, 1536, 256, 2LL * m * m, (long long)m * m, 2);
      softmax_pb_k<<<6 * m, 256, 0, stream>>>(SC, m, mpad);
      // attn @ V: Pb in-place over SC, lda = 2m, batch strides {4m^2, 2m^2}
      bgemm(stream, 3, false, false, (bf16*)SC, nullptr, VT, nullptr, ATTOb, nullptr,
            nullptr, nullptr, nullptr, nullptr, nullptr, 0,
            m, 256, mpad, 2 * m, mpad, 1536, 1.f,
            6, 4LL * m * m, 2LL * m * m, 2LL * 256 * mpad, 256LL * mpad, 512, 256, 2);
      bgemm(stream, 0, false, true, ATTOb, nullptr, outhi + (long long)i * 262144,
            outlo + (long long)i * 262144, XB, nullptr, nullptr,
            out_b + i * 512, nullptr, nullptr, nullptr, 0,
            T, 512, 512, 512, 512, 512, 1.f);
      ln_k<<<T, 256, 0, stream>>>(curhi, curlo, XB, ln1_w + i * 512, ln1_b + i * 512,
                                  nxthi, nxtlo);
      bgemm(stream, 4, true, true, nxthi, nxtlo, ff1hi + (long long)i * 262144,
            ff1lo + (long long)i * 262144, XChi, XClo, nullptr,
            ff1_b + i * 512, nullptr, nullptr, nullptr, 0,
            T, 512, 512, 512, 512, 512, 1.f);
      bgemm(stream, 0, true, true, XChi, XClo, ff2hi + (long long)i * 262144,
            ff2lo + (long long)i * 262144, XB, nullptr, nullptr,
            ff2_b + i * 512, nullptr, nullptr, nullptr, 0,
            T, 512, 512, 512, 512, 512, 1.f);
      ln_k<<<T, 256, 0, stream>>>(nxthi, nxtlo, XB, ln2_w + i * 512, ln2_b + i * 512,
                                  curhi, curlo);
    }

    // iou: in-place accumulate into IOU_all rows [off, off+m) with b_iou
    bgemm(stream, 5, true, true, curhi, curlo, Uihi, Uilo,
          IOUa + (long long)off * 1536, nullptr, IOUa + (long long)off * 1536,
          b_iou, nullptr, nullptr, nullptr, 0, m, 1536, 1536, 1536, 1536, 1536, 1.f);
    combine_k<<<(m * 512 + 255) / 256, 256, 0, stream>>>(
        IOUa + (long long)off * 1536, CRED, Cc, Hhi, Hlo, off, m, tl, tl / 3,
        l > 0 ? RAhi : nullptr, l > 0 ? RAlo : nullptr);
  }

  // 4) merged decoders: weights strictly OUTSIDE d_out (ws pools or streamed d_in)
  if (wsfit) {
    bgemm(stream, 6, true, true, Hhi, Hlo, DhiW, DloW, ob, nullptr, nullptr,
          dpb, dcb, dgb, nullptr, 0, NN, 6324, 512, 512, 512, 0, 1.f);
  } else {
    bgemm(stream, 6, true, true, Hhi, Hlo, nullptr, nullptr, ob, nullptr, nullptr,
          dpb, dcb, dgb, nullptr, 0, NN, 6324, 512, 512, 512, 0, 1.f,
          1, 0, 0, 0, 0, 0, 0, 1, dpw, dcw, dgw, true);
  }
}

// Round 10
// 2653.853 us; speedup vs baseline: 1.0619x; 1.0048x over previous
//
#include <hip/hip_runtime.h>
#include <hip/hip_bf16.h>

// TreeLSTM forward, round 10: round-9 numerics (bit-identical) +
// - 2-phase double-buffered K-loop (raw s_barrier + counted vmcnt) for dispatches
//   with <=256 blocks (latency-bound small/mid GEMMs); big GEMMs keep proven path
// - bijective XCD swizzle on the decoder GEMM (HBM-bound, L2 locality)
// Topology: 16 perfect ternary trees, depth 6; off[l] l=0..5: {5808,5760,5616,5184,3888,0}.

namespace {

constexpr int NN = 5824;
constexpr int ED = 352;

typedef __bf16 bf16;
typedef short s16x8 __attribute__((ext_vector_type(8)));
typedef float f32x4 __attribute__((ext_vector_type(4)));

__device__ __forceinline__ float sigmoidf_(float x) { return 1.f / (1.f + expf(-x)); }

__device__ __forceinline__ void gload_lds16(const void* g, void* s) {
  __builtin_amdgcn_global_load_lds(
      (const __attribute__((address_space(1))) unsigned int*)g,
      (__attribute__((address_space(3))) unsigned int*)s, 16, 0, 0);
}

// ---------------- bf16 MFMA GEMM ----------------
// C = alpha * (A_hi [+ A_lo]) @ (B_hi [+ B_lo])^T + bias [+Cacc] [relu]
// MFMA stream order fixed: A_hi*B_hi [+ A_hi*B_lo if BPAIR] [+ A_lo*B_hi if DUAL].
// PIPE: 2-phase double-buffered K-loop (prefetch next tile under current MFMA).
// MODE 0: f32 out (+bias)   MODE 3: bf16 out   MODE 4: pair+relu+bias
// MODE 5: f32+bias+accum    MODE 6: decoder region-select (+XCD swizzle)
// MODE 7: bf16+bias+VT scatter (incl. K-pad zero fill)
template <int MODE, bool DUAL, bool BPAIR, bool BF32, bool PIPE>
__global__ __launch_bounds__(256) void bgemm_k(
    const bf16* __restrict__ A, const bf16* __restrict__ Alo,
    const bf16* __restrict__ Bh_, const bf16* __restrict__ Bl_,
    const float* __restrict__ Bf0, const float* __restrict__ Bf1,
    const float* __restrict__ Bf2,
    void* __restrict__ Cp, bf16* __restrict__ Clo, const float* __restrict__ Cacc,
    const float* __restrict__ bias, const float* __restrict__ bias1,
    const float* __restrict__ bias2, bf16* __restrict__ VTout, int mpad,
    int M, int N, int K, int lda, int ldb, int ldc, float alpha,
    long long sA1, long long sA2, long long sB1, long long sB2,
    long long sC1, long long sC2, int nh) {
  const int bz = blockIdx.z;
  const int b1 = bz / nh, b2 = bz - b1 * nh;
  A += (long long)b1 * sA1 + (long long)b2 * sA2;
  if (DUAL) Alo += (long long)b1 * sA1 + (long long)b2 * sA2;
  if (!BF32) {
    Bh_ += (long long)b1 * sB1 + (long long)b2 * sB2;
    if (BPAIR) Bl_ += (long long)b1 * sB1 + (long long)b2 * sB2;
  }
  const long long coff = (long long)b1 * sC1 + (long long)b2 * sC2;

  int bxx = blockIdx.x, byy = blockIdx.y;
  if (MODE == 6) {
    // bijective XCD-aware remap (m204): contiguous chunk of tiles per XCD
    int nwg = gridDim.x * gridDim.y;
    int orig = byy * gridDim.x + bxx;
    int q = nwg >> 3, r = nwg & 7;
    int xcd = orig & 7, idx = orig >> 3;
    int wg = (xcd < r ? xcd * (q + 1) : r * (q + 1) + (xcd - r) * q) + idx;
    bxx = wg % gridDim.x;
    byy = wg / gridDim.x;
  }
  const int bm = byy * 128, bn = bxx * 128;

  constexpr int NSTG = PIPE ? 2 : 1;
  __shared__ bf16 As[NSTG][128 * 32];
  __shared__ bf16 Ls[DUAL ? NSTG : 1][DUAL ? 128 * 32 : 8];
  __shared__ bf16 Bh[NSTG][128 * 32];
  __shared__ bf16 Bl[BPAIR ? NSTG : 1][BPAIR ? 128 * 32 : 8];
  const int tid = threadIdx.x;
  const int l = tid & 63;
  const int wr = ((tid >> 7) & 1) * 64;
  const int wc = ((tid >> 6) & 1) * 64;
  f32x4 acc[4][4];
#pragma unroll
  for (int i = 0; i < 4; ++i)
#pragma unroll
    for (int j = 0; j < 4; ++j) acc[i][j] = (f32x4){0.f, 0.f, 0.f, 0.f};

  auto STAGE = [&](int st, int k0) {
#pragma unroll
    for (int r = 0; r < 2; ++r) {
      int idx = r * 256 + tid;
      int row = idx >> 2, cs = idx & 3;
      int cg = cs ^ (row & 3);
      int ra = bm + row; if (ra > M - 1) ra = M - 1;
      int rb = bn + row; if (rb > N - 1) rb = N - 1;
      gload_lds16(A + (long long)ra * lda + k0 + cg * 8, &As[st][idx * 8]);
      if (DUAL) gload_lds16(Alo + (long long)ra * lda + k0 + cg * 8, &Ls[st][idx * 8]);
      if (BF32) {
        const float* src;
        if (rb < 5000)      src = Bf0 + (long long)rb * ldb + k0 + cg * 8;
        else if (rb < 5300) src = Bf1 + (long long)(rb - 5000) * ldb + k0 + cg * 8;
        else                src = Bf2 + (long long)(rb - 5300) * ldb + k0 + cg * 8;
        float4 x = *reinterpret_cast<const float4*>(src);
        float4 y = *reinterpret_cast<const float4*>(src + 4);
        float w[8] = {x.x, x.y, x.z, x.w, y.x, y.y, y.z, y.w};
        bf16 hb_[8], lb_[8];
#pragma unroll
        for (int q = 0; q < 8; ++q) {
          bf16 hq = (bf16)w[q];
          hb_[q] = hq;
          lb_[q] = (bf16)(w[q] - (float)hq);
        }
        *reinterpret_cast<s16x8*>(&Bh[st][idx * 8]) = *reinterpret_cast<s16x8*>(hb_);
        *reinterpret_cast<s16x8*>(&Bl[st][idx * 8]) = *reinterpret_cast<s16x8*>(lb_);
      } else {
        gload_lds16(Bh_ + (long long)rb * ldb + k0 + cg * 8, &Bh[st][idx * 8]);
        if (BPAIR) gload_lds16(Bl_ + (long long)rb * ldb + k0 + cg * 8, &Bl[st][idx * 8]);
      }
    }
  };

  auto COMPUTE = [&](int st) {
    s16x8 af[4], al[4], bh4[4], bl4[4];
#pragma unroll
    for (int mi = 0; mi < 4; ++mi) {
      int row = wr + mi * 16 + (l & 15);
      int ch = ((l >> 4) ^ row) & 3;
      af[mi] = *reinterpret_cast<const s16x8*>(&As[st][row * 32 + ch * 8]);
      if (DUAL) al[mi] = *reinterpret_cast<const s16x8*>(&Ls[st][row * 32 + ch * 8]);
    }
#pragma unroll
    for (int ni = 0; ni < 4; ++ni) {
      int row = wc + ni * 16 + (l & 15);
      int ch = ((l >> 4) ^ row) & 3;
      bh4[ni] = *reinterpret_cast<const s16x8*>(&Bh[st][row * 32 + ch * 8]);
      if (BPAIR) bl4[ni] = *reinterpret_cast<const s16x8*>(&Bl[st][row * 32 + ch * 8]);
    }
#pragma unroll
    for (int mi = 0; mi < 4; ++mi)
#pragma unroll
      for (int ni = 0; ni < 4; ++ni) {
        acc[mi][ni] =
            __builtin_amdgcn_mfma_f32_16x16x32_bf16(af[mi], bh4[ni], acc[mi][ni], 0, 0, 0);
        if (BPAIR)
          acc[mi][ni] =
              __builtin_amdgcn_mfma_f32_16x16x32_bf16(af[mi], bl4[ni], acc[mi][ni], 0, 0, 0);
        if (DUAL)
          acc[mi][ni] =
              __builtin_amdgcn_mfma_f32_16x16x32_bf16(al[mi], bh4[ni], acc[mi][ni], 0, 0, 0);
      }
  };

  if (!PIPE) {
    for (int k0 = 0; k0 < K; k0 += 32) {
      STAGE(0, k0);
      __syncthreads();
      COMPUTE(0);
      __syncthreads();
    }
  } else {
    // 2-phase: prefetch next K-tile under current MFMA (T3 minimum recipe).
    STAGE(0, 0);
    asm volatile("s_waitcnt vmcnt(0)" ::: "memory");
    __builtin_amdgcn_s_barrier();
    int cur = 0;
    for (int k0 = 0; k0 < K; k0 += 32) {
      if (k0 + 32 < K) STAGE(cur ^ 1, k0 + 32);  // issue loads for next tile
      COMPUTE(cur);                               // MFMA on current tile
      asm volatile("s_waitcnt vmcnt(0)" ::: "memory");
      __builtin_amdgcn_sched_barrier(0);
      __builtin_amdgcn_s_barrier();               // next tile ready; cur readers done
      cur ^= 1;
    }
  }

  const int lc = l & 15, lr4 = (l >> 4) * 4;
#pragma unroll
  for (int mi = 0; mi < 4; ++mi) {
#pragma unroll
    for (int j = 0; j < 4; ++j) {
      int r = bm + wr + mi * 16 + lr4 + j;
      if (MODE != 7 && r >= M) continue;
#pragma unroll
      for (int ni = 0; ni < 4; ++ni) {
        int c = bn + wc + ni * 16 + lc;
        if (c >= N) continue;
        float v = alpha * acc[mi][ni][j];
        if (MODE == 6) {
          v += (c < 5000) ? bias[c] : (c < 5300) ? bias1[c - 5000] : bias2[c - 5300];
        } else if (bias) {
          v += bias[c];
        }
        long long idx = coff + (long long)r * ldc + c;
        if (MODE == 7) {
          if (c >= 1024 && r < 3 * mpad) {
            bf16 pv = (r < M) ? (bf16)v : (bf16)0.f;
            int r3 = r % 3, s = r / 3;
            int hh = (c - 1024) >> 8, n = (c - 1024) & 255;
            VTout[(long long)((r3 * 2 + hh) * 256 + n) * mpad + s] = pv;
          }
          if (r < M) ((bf16*)Cp)[idx] = (bf16)v;
        } else if (MODE == 5) {
          ((float*)Cp)[idx] = v + Cacc[idx];
        } else if (MODE == 0) {
          ((float*)Cp)[idx] = v;
        } else if (MODE == 3) {
          ((bf16*)Cp)[idx] = (bf16)v;
        } else if (MODE == 4) {
          v = fmaxf(v, 0.f);
          bf16 hv = (bf16)v;
          ((bf16*)Cp)[idx] = hv;
          Clo[idx] = (bf16)(v - (float)hv);
        } else {  // MODE 6: decoder region select (poi 5000 | cat 300 | coo 1024)
          float* o0 = (float*)Cp;
          if (c < 5000)      o0[(long long)r * 5000 + c] = v;
          else if (c < 5300) o0[29120000LL + (long long)r * 300 + (c - 5000)] = v;
          else               o0[30867200LL + (long long)r * 1024 + (c - 5300)] = v;
        }
      }
    }
  }
}

static void bgemm(hipStream_t st, int mode, bool dual, bool bpair,
                  const bf16* A, const bf16* Alo, const bf16* Bh, const bf16* Bl,
                  void* Cp, bf16* Clo, const float* Cacc,
                  const float* bias, const float* bias1, const float* bias2,
                  bf16* VTout, int mpad,
                  int M, int N, int K, int lda, int ldb, int ldc, float alpha,
                  int batches = 1, long long sA1 = 0, long long sA2 = 0,
                  long long sB1 = 0, long long sB2 = 0, long long sC1 = 0,
                  long long sC2 = 0, int nh = 1,
                  const float* Bf0 = nullptr, const float* Bf1 = nullptr,
                  const float* Bf2 = nullptr, bool bf32 = false) {
  dim3 g((N + 127) / 128, (M + 127) / 128, batches), b(256);
  long long nblocks = (long long)g.x * g.y * g.z;
  const bool pipe = (!bf32) && nblocks <= 256;
#define BGL(MD_, DU_, BP_, BFF_, PP_)                                                    \
  bgemm_k<MD_, DU_, BP_, BFF_, PP_><<<g, b, 0, st>>>(                                    \
      A, Alo, Bh, Bl, Bf0, Bf1, Bf2, Cp, Clo, Cacc, bias, bias1, bias2, VTout, mpad,     \
      M, N, K, lda, ldb, ldc, alpha, sA1, sA2, sB1, sB2, sC1, sC2, nh)
#define BGL2(MD_, DU_, BP_)                                                              \
  do { if (pipe) BGL(MD_, DU_, BP_, false, true); else BGL(MD_, DU_, BP_, false, false); \
  } while (0)
  if (mode == 0 && !dual && bpair)        BGL2(0, false, true);
  else if (mode == 0 && dual && bpair)    BGL2(0, true, true);
  else if (mode == 0 && !dual && !bpair)  BGL2(0, false, false);
  else if (mode == 3)                     BGL2(3, false, false);
  else if (mode == 4)                     BGL2(4, true, true);
  else if (mode == 5)                     BGL2(5, true, true);
  else if (mode == 6 && !bf32)            BGL(6, true, true, false, false);
  else if (mode == 6 && bf32)             BGL(6, true, true, true, false);
  else                                    BGL2(7, true, true);
#undef BGL2
#undef BGL
}

// ---------------- fp32 -> (hi, lo) bf16 split, segmented; ptrs computed on host ------
struct SegArgs {
  const float* src[8];
  bf16* hi[8];
  bf16* lo[8];
  int start[9];  // prefix sums in 8-element units; trailing entries = total
};
__global__ __launch_bounds__(256) void split_k(SegArgs a, int total8) {
  for (int i = blockIdx.x * 256 + threadIdx.x; i < total8; i += gridDim.x * 256) {
    int s = 0;
    while (i >= a.start[s + 1]) ++s;
    long long off = (long long)(i - a.start[s]) * 8;
    const float4* p = reinterpret_cast<const float4*>(a.src[s] + off);
    float4 x = p[0], y = p[1];
    float w[8] = {x.x, x.y, x.z, x.w, y.x, y.y, y.z, y.w};
    bf16 hb[8], lb[8];
#pragma unroll
    for (int q = 0; q < 8; ++q) {
      bf16 hq = (bf16)w[q];
      hb[q] = hq;
      lb[q] = (bf16)(w[q] - (float)hq);
    }
    *reinterpret_cast<s16x8*>(a.hi[s] + off) = *reinterpret_cast<s16x8*>(hb);
    *reinterpret_cast<s16x8*>(a.lo[s] + off) = *reinterpret_cast<s16x8*>(lb);
  }
}

// ---------------- embedding gather + concat + time-pos + mask -> bf16 ----------------
__global__ __launch_bounds__(256) void embed_k(
    const int* __restrict__ uid, const int* __restrict__ pid, const int* __restrict__ cid,
    const int* __restrict__ gid, const int* __restrict__ tmid, const int* __restrict__ mask,
    const float* __restrict__ ue, const float* __restrict__ pe, const float* __restrict__ ce,
    const float* __restrict__ ge, const float* __restrict__ tp, bf16* __restrict__ xb) {
  int e = blockIdx.x * 256 + threadIdx.x;
  if (e >= NN * ED) return;
  int n = e / ED, j = e - n * ED;
  int mi = mask[n];
  float fm = (float)mi;
  float v;
  if (j < 128)      v = ue[(long long)(uid[n] * mi) * 128 + j];
  else if (j < 256) v = pe[(long long)(pid[n] * mi) * 128 + (j - 128)];
  else if (j < 288) v = ce[(long long)(cid[n] * mi) * 32 + (j - 256)];
  else              v = ge[(long long)(gid[n] * mi) * 64 + (j - 288)];
  v += 0.5f * tp[(long long)(tmid[n] * mi) * ED + j];
  xb[e] = (bf16)(v * fm);
}

// ---------------- forget gates + c_red (reads children's c directly) ----------------
__global__ __launch_bounds__(256) void fcred_k(
    const float* __restrict__ wxa, const float* __restrict__ ufh,
    const float* __restrict__ bf_, const float* __restrict__ c, float* __restrict__ cred,
    int m, int cbase, int tl, int woff) {
  int e = blockIdx.x * 256 + threadIdx.x;
  if (e >= m * 512) return;
  int r = e >> 9, d = e & 511;
  float w = wxa[(long long)(woff + r) * 512 + d] + bf_[d];
  int t = r / tl, p = r - t * tl;
  long long cb = (long long)(cbase + t * 3 * tl + 3 * p) * 512 + d;
  long long ub = (long long)r * 1536;
  float acc = 0.f;
#pragma unroll
  for (int k = 0; k < 3; ++k) {
    float f = sigmoidf_(w + ufh[ub + k * 512 + d]);
    acc += f * c[cb + (long long)k * 512];
  }
  cred[e] = acc;
}

// ---------------- iou -> (h,c); h pair + scatter into next level's mailbox ----------
__global__ __launch_bounds__(256) void combine_k(
    const float* __restrict__ iou, const float* __restrict__ cred, float* __restrict__ c,
    bf16* __restrict__ hhi, bf16* __restrict__ hlo, int off, int m, int tl3, int tlp,
    bf16* __restrict__ nxthi, bf16* __restrict__ nxtlo) {
  int e = blockIdx.x * 256 + threadIdx.x;
  if (e >= m * 512) return;
  int r = e >> 9, d = e & 511;
  long long b = (long long)r * 1536;
  float iv = iou[b + d], ov = iou[b + 512 + d], uv = iou[b + 1024 + d];
  float cr = cred ? cred[e] : 0.f;
  float cn = sigmoidf_(iv) * tanhf(uv) + cr;
  float hn = sigmoidf_(ov) * tanhf(cn);
  long long o = (long long)(off + r) * 512 + d;
  c[o] = cn;
  bf16 hv = (bf16)hn;
  bf16 lo = (bf16)(hn - (float)hv);
  hhi[o] = hv;
  hlo[o] = lo;
  if (nxthi) {
    int t = r / tl3, q = r - t * tl3;
    int qp = q / 3, slot = q - 3 * qp;
    long long dst = (long long)(t * tlp + qp) * 1536 + slot * 512 + d;
    nxthi[dst] = hv;
    nxtlo[dst] = lo;
  }
}

// ---------------- LayerNorm width 512: LN((ahi+alo) + b)*w + bias -> pair ----------
__global__ __launch_bounds__(256) void ln_k(
    const bf16* __restrict__ ahi, const bf16* __restrict__ alo, const float* __restrict__ b,
    const float* __restrict__ w, const float* __restrict__ bias,
    bf16* __restrict__ ohi, bf16* __restrict__ olo) {
  int r = blockIdx.x, t = threadIdx.x;
  long long base = (long long)r * 512;
  float v0 = (float)ahi[base + t] + (float)alo[base + t] + b[base + t];
  float v1 = (float)ahi[base + 256 + t] + (float)alo[base + 256 + t] + b[base + 256 + t];
  __shared__ float s1[256], s2[256];
  s1[t] = v0 + v1;
  s2[t] = v0 * v0 + v1 * v1;
  __syncthreads();
  for (int s = 128; s > 0; s >>= 1) {
    if (t < s) { s1[t] += s1[t + s]; s2[t] += s2[t + s]; }
    __syncthreads();
  }
  float mu = s1[0] * (1.f / 512.f);
  float var = s2[0] * (1.f / 512.f) - mu * mu;
  float rs = rsqrtf(var + 1e-5f);
  float o0 = (v0 - mu) * rs * w[t] + bias[t];
  float o1 = (v1 - mu) * rs * w[256 + t] + bias[256 + t];
  bf16 h0 = (bf16)o0, h1 = (bf16)o1;
  ohi[base + t] = h0;       olo[base + t] = (bf16)(o0 - (float)h0);
  ohi[base + 256 + t] = h1; olo[base + 256 + t] = (bf16)(o1 - (float)h1);
}

// ---------------- row softmax fp32 -> bf16 probs IN PLACE over SC ----------------
// Pb row r = (bf16*)sc + r*2m (within row r's own fp32 storage); pads [m,mpad)=0.
__global__ __launch_bounds__(256) void softmax_pb_k(float* __restrict__ sc, int m, int mpad) {
  long long r = blockIdx.x;
  float* row = sc + r * (long long)m;
  bf16* prow = (bf16*)sc + r * (long long)(2 * m);
  int t = threadIdx.x;
  __shared__ float sh[256];
  float mx = -3.4e38f;
  for (int j = t; j < m; j += 256) mx = fmaxf(mx, row[j]);
  sh[t] = mx;
  __syncthreads();
  for (int s = 128; s > 0; s >>= 1) {
    if (t < s) sh[t] = fmaxf(sh[t], sh[t + s]);
    __syncthreads();
  }
  mx = sh[0];
  __syncthreads();
  float ev[6];  // ceil(1296/256) = 6 max
  float sum = 0.f;
  int cnt = 0;
  for (int j = t; j < m; j += 256) {
    float e = expf(row[j] - mx);
    ev[cnt++] = e;
    sum += e;
  }
  sh[t] = sum;
  __syncthreads();
  for (int s = 128; s > 0; s >>= 1) {
    if (t < s) sh[t] += sh[t + s];
    __syncthreads();
  }
  float inv = 1.f / sh[0];
  cnt = 0;
  for (int j = t; j < m; j += 256) prow[j] = (bf16)(ev[cnt++] * inv);
  for (int j = m + t; j < mpad; j += 256) prow[j] = (bf16)0.f;
}

}  // namespace

extern "C" void kernel_launch(void* const* d_in, const int* in_sizes, int n_in,
                              void* d_out, int out_size, void* d_ws, size_t ws_size,
                              hipStream_t stream) {
  const int* uid  = (const int*)d_in[0];
  const int* pid  = (const int*)d_in[1];
  const int* cid  = (const int*)d_in[2];
  const int* gid  = (const int*)d_in[3];
  const int* tmid = (const int*)d_in[4];
  const int* mask = (const int*)d_in[5];
  const float* ue = (const float*)d_in[6];
  const float* pe = (const float*)d_in[7];
  const float* ce = (const float*)d_in[8];
  const float* ge = (const float*)d_in[9];
  const float* tp = (const float*)d_in[10];
  const float* b_iou = (const float*)d_in[13];
  const float* b_f = (const float*)d_in[16];
  const float* qkv_b = (const float*)d_in[18];
  const float* out_b = (const float*)d_in[20];
  const float* ln1_w = (const float*)d_in[21];
  const float* ln1_b = (const float*)d_in[22];
  const float* ff1_b = (const float*)d_in[24];
  const float* ff2_b = (const float*)d_in[26];
  const float* ln2_w = (const float*)d_in[27];
  const float* ln2_b = (const float*)d_in[28];
  const float* dpw = (const float*)d_in[29];
  const float* dpb = (const float*)d_in[30];
  const float* dcw = (const float*)d_in[31];
  const float* dcb = (const float*)d_in[32];
  const float* dgw = (const float*)d_in[33];
  const float* dgb = (const float*)d_in[34];

  // ---- d_ws: H pair bf16 [0, 11.9MB), Cc fp32 [11.9, 23.9MB),
  //      decoder hi/lo pools [23.9, 36.8MB) IF ws_size permits ----
  float* ws = (float*)d_ws;
  bf16* Hhi = (bf16*)ws;
  bf16* Hlo = Hhi + 2981888LL;
  float* Cc = ws + 2981888LL;
  bf16* DhiW = (bf16*)(ws + 5963776LL);        // 3,237,888 el
  bf16* DloW = DhiW + 3237888LL;               // ends fl 9,201,664 (36,806,656 B)
  const bool wsfit = ws_size >= 36806656ULL;

  // ---- d_out map (fl offsets) ----
  float* ob = (float*)d_out;
  float* IOUa = ob;                            // [0, 8,945,664)
  float* WXa  = ob + 8945664LL;                // [.., 9,936,896)
  float* CRED = ob + 9936896LL;                // [.., 10,600,448)
  bf16* RAhi  = (bf16*)(ob + 10600448LL);      // 1,990,656 el
  bf16* RAlo  = RAhi + 1990656LL;
  bf16* RBhi  = (bf16*)(ob + 12591104LL);
  bf16* RBlo  = RBhi + 1990656LL;
  bf16* UP    = (bf16*)(ob + 14581760LL);      // U pool: 9,437,184 el
  bf16* TE    = (bf16*)(ob + 19300352LL);      // TE pool: 6,291,456 el
  float* TB   = ob + 22446080LL;               // transient, 14,384,896 fl

  // U pool
  bf16* Uihi = UP;                  // U_iou hi (2,359,296)
  bf16* Uilo = UP + 2359296LL;
  bf16* Ufhi = UP + 4718592LL;      // U_f hi
  bf16* Uflo = UP + 7077888LL;
  // TE pool
  bf16* qkvhi = TE;                 // 1,572,864 (2 layers)
  bf16* qkvlo = TE + 1572864LL;
  bf16* outhi = TE + 3145728LL;     // 524,288
  bf16* outlo = TE + 3670016LL;
  bf16* ff1hi = TE + 4194304LL;
  bf16* ff1lo = TE + 4718592LL;
  bf16* ff2hi = TE + 5242880LL;
  bf16* ff2lo = TE + 5767168LL;

  // TB layout during level loop:
  float* SC   = TB;                            // [0, 10,077,696) fp32; Pb aliased inside
  float* PQ   = TB + 10077696LL;               // [.., 13,063,680): UFH / QKVb / ATTOb
  bf16* VT    = (bf16*)(TB + 13063680LL);      // 2,015,232 el -> ends TB+14,071,296
  // early-phase aliases in TB (dead before SC first written at level-4 scores):
  bf16* Xb    = (bf16*)TB;                     // 2,050,048 el = 1,025,024 fl
  bf16* WP    = (bf16*)(TB + 1025024LL);       // W pool: 1,441,792 el
  bf16* Wihi  = WP;
  bf16* Wilo  = WP + 540672LL;
  bf16* Wfhi  = WP + 1081344LL;
  bf16* Wflo  = WP + 1261568LL;

  float* UFH  = PQ;
  bf16* QKVb  = (bf16*)PQ;
  bf16* ATTOb = (bf16*)PQ;
  float* XB   = TB;                            // fp32, after Pb dead
  bf16* XChi  = (bf16*)(TB + 1990656LL);
  bf16* XClo  = (bf16*)(TB + 2985984LL);

  // 0) split all level-loop weights into hi/lo pools; decoder weights into d_ws
  {
    SegArgs a{};
    const int n8[8] = {294912, 294912, 196608, 65536, 65536, 65536, 67584, 22528};
    a.src[0] = (const float*)d_in[12]; a.hi[0] = Uihi;  a.lo[0] = Uilo;   // U_iou
    a.src[1] = (const float*)d_in[15]; a.hi[1] = Ufhi;  a.lo[1] = Uflo;   // U_f
    a.src[2] = (const float*)d_in[17]; a.hi[2] = qkvhi; a.lo[2] = qkvlo;  // qkv_w
    a.src[3] = (const float*)d_in[19]; a.hi[3] = outhi; a.lo[3] = outlo;  // out_w
    a.src[4] = (const float*)d_in[23]; a.hi[4] = ff1hi; a.lo[4] = ff1lo;  // ff1_w
    a.src[5] = (const float*)d_in[25]; a.hi[5] = ff2hi; a.lo[5] = ff2lo;  // ff2_w
    a.src[6] = (const float*)d_in[11]; a.hi[6] = Wihi;  a.lo[6] = Wilo;   // W_iou
    a.src[7] = (const float*)d_in[14]; a.hi[7] = Wfhi;  a.lo[7] = Wflo;   // W_f
    a.start[0] = 0;
    for (int i = 0; i < 8; ++i) a.start[i + 1] = a.start[i] + n8[i];
    int total8 = a.start[8];
    int blocks = (total8 + 255) / 256; if (blocks > 4096) blocks = 4096;
    split_k<<<blocks, 256, 0, stream>>>(a, total8);
    if (wsfit) {
      SegArgs d{};
      const int dn8[3] = {320000, 19200, 65536};
      d.src[0] = dpw; d.hi[0] = DhiW;             d.lo[0] = DloW;
      d.src[1] = dcw; d.hi[1] = DhiW + 2560000LL; d.lo[1] = DloW + 2560000LL;
      d.src[2] = dgw; d.hi[2] = DhiW + 2713600LL; d.lo[2] = DloW + 2713600LL;
      d.start[0] = 0;
      for (int i = 0; i < 3; ++i) d.start[i + 1] = d.start[i] + dn8[i];
      for (int i = 3; i < 8; ++i) d.start[i + 1] = d.start[3];
      int dt8 = d.start[3];
      int db = (dt8 + 255) / 256; if (db > 4096) db = 4096;
      split_k<<<db, 256, 0, stream>>>(d, dt8);
    }
  }

  // 1) embeddings
  embed_k<<<(NN * ED + 255) / 256, 256, 0, stream>>>(uid, pid, cid, gid, tmid, mask,
                                                     ue, pe, ce, ge, tp, Xb);

  // 2) hoisted projections: IOU_all (no bias), WX_all
  bgemm(stream, 0, false, true, Xb, nullptr, Wihi, Wilo, IOUa, nullptr, nullptr,
        nullptr, nullptr, nullptr, nullptr, 0, NN, 1536, 352, 352, 352, 1536, 1.f);
  bgemm(stream, 0, false, true, Xb + 3888LL * ED, nullptr, Wfhi, Wflo, WXa, nullptr,
        nullptr, nullptr, nullptr, nullptr, nullptr, 0, 1936, 512, 352, 352, 352, 512, 1.f);

  // 3) leaves: combine + scatter into level-4 mailbox RA
  combine_k<<<(3888 * 512 + 255) / 256, 256, 0, stream>>>(
      IOUa, nullptr, Cc, Hhi, Hlo, 0, 3888, 243, 81, RAhi, RAlo);

  static const int OFFL[6] = {5808, 5760, 5616, 5184, 3888, 0};
  int tl = 81;
  for (int l = 4; l >= 0; --l, tl /= 3) {
    int m = 16 * tl;
    int off = OFFL[l];
    int cbase = OFFL[l + 1];
    int T = 3 * m;
    int mpad = (m + 31) & ~31;

    bgemm(stream, 0, true, true, RAhi, RAlo, Ufhi, Uflo, UFH, nullptr, nullptr,
          nullptr, nullptr, nullptr, nullptr, 0, m, 1536, 1536, 1536, 1536, 1536, 1.f);
    fcred_k<<<(m * 512 + 255) / 256, 256, 0, stream>>>(WXa, UFH, b_f, Cc, CRED,
                                                       m, cbase, tl, off - 3888);

    bf16 *curhi = RAhi, *curlo = RAlo, *nxthi = RBhi, *nxtlo = RBlo;
    for (int i = 0; i < 2; ++i) {
      // qkv (+fused V^T scatter with zero-filled K-pad)
      bgemm(stream, 7, true, true, curhi, curlo, qkvhi + (long long)i * 786432,
            qkvlo + (long long)i * 786432, QKVb, nullptr, nullptr,
            qkv_b + i * 1536, nullptr, nullptr, VT, mpad,
            T, 1536, 512, 512, 512, 1536, 1.f);
      // scores = (1/16) Q@K^T
      bgemm(stream, 0, false, false, QKVb, nullptr, QKVb + 512, nullptr, SC, nullptr,
            nullptr, nullptr, nullptr, nullptr, nullptr, 0,
            m, m, 256, 4608, 4608, m, 0.0625f,
            6, 1536, 256, 1536, 256, 2LL * m * m, (long long)m * m, 2);
      softmax_pb_k<<<6 * m, 256, 0, stream>>>(SC, m, mpad);
      // attn @ V: Pb in-place over SC, lda = 2m, batch strides {4m^2, 2m^2}
      bgemm(stream, 3, false, false, (bf16*)SC, nullptr, VT, nullptr, ATTOb, nullptr,
            nullptr, nullptr, nullptr, nullptr, nullptr, 0,
            m, 256, mpad, 2 * m, mpad, 1536, 1.f,
            6, 4LL * m * m, 2LL * m * m, 2LL * 256 * mpad, 256LL * mpad, 512, 256, 2);
      bgemm(stream, 0, false, true, ATTOb, nullptr, outhi + (long long)i * 262144,
            outlo + (long long)i * 262144, XB, nullptr, nullptr,
            out_b + i * 512, nullptr, nullptr, nullptr, 0,
            T, 512, 512, 512, 512, 512, 1.f);
      ln_k<<<T, 256, 0, stream>>>(curhi, curlo, XB, ln1_w + i * 512, ln1_b + i * 512,
                                  nxthi, nxtlo);
      bgemm(stream, 4, true, true, nxthi, nxtlo, ff1hi + (long long)i * 262144,
            ff1lo + (long long)i * 262144, XChi, XClo, nullptr,
            ff1_b + i * 512, nullptr, nullptr, nullptr, 0,
            T, 512, 512, 512, 512, 512, 1.f);
      bgemm(stream, 0, true, true, XChi, XClo, ff2hi + (long long)i * 262144,
            ff2lo + (long long)i * 262144, XB, nullptr, nullptr,
            ff2_b + i * 512, nullptr, nullptr, nullptr, 0,
            T, 512, 512, 512, 512, 512, 1.f);
      ln_k<<<T, 256, 0, stream>>>(nxthi, nxtlo, XB, ln2_w + i * 512, ln2_b + i * 512,
                                  curhi, curlo);
    }

    // iou: in-place accumulate into IOU_all rows [off, off+m) with b_iou
    bgemm(stream, 5, true, true, curhi, curlo, Uihi, Uilo,
          IOUa + (long long)off * 1536, nullptr, IOUa + (long long)off * 1536,
          b_iou, nullptr, nullptr, nullptr, 0, m, 1536, 1536, 1536, 1536, 1536, 1.f);
    combine_k<<<(m * 512 + 255) / 256, 256, 0, stream>>>(
        IOUa + (long long)off * 1536, CRED, Cc, Hhi, Hlo, off, m, tl, tl / 3,
        l > 0 ? RAhi : nullptr, l > 0 ? RAlo : nullptr);
  }

  // 4) merged decoders: weights strictly OUTSIDE d_out (ws pools or streamed d_in)
  if (wsfit) {
    bgemm(stream, 6, true, true, Hhi, Hlo, DhiW, DloW, ob, nullptr, nullptr,
          dpb, dcb, dgb, nullptr, 0, NN, 6324, 512, 512, 512, 0, 1.f);
  } else {
    bgemm(stream, 6, true, true, Hhi, Hlo, nullptr, nullptr, ob, nullptr, nullptr,
          dpb, dcb, dgb, nullptr, 0, NN, 6324, 512, 512, 512, 0, 1.f,
          1, 0, 0, 0, 0, 0, 0, 1, dpw, dcw, dgw, true);
  }
}

// Round 11
// 2562.208 us; speedup vs baseline: 1.0999x; 1.0358x over previous
//
#include <hip/hip_runtime.h>
#include <hip/hip_bf16.h>

// TreeLSTM forward, round 11:
// - decoder XCD swizzle REVERTED (round-10 counters: FETCH +28%, 165->197us regression)
// - decoder GEMM single-stream hi*hi (final op, error bounded ~3e-3; 3x less MFMA)
// - PIPE (2-phase dbuf K-loop) threshold raised to <=1024 blocks
// Topology: 16 perfect ternary trees, depth 6; off[l] l=0..5: {5808,5760,5616,5184,3888,0}.

namespace {

constexpr int NN = 5824;
constexpr int ED = 352;

typedef __bf16 bf16;
typedef short s16x8 __attribute__((ext_vector_type(8)));
typedef float f32x4 __attribute__((ext_vector_type(4)));

__device__ __forceinline__ float sigmoidf_(float x) { return 1.f / (1.f + expf(-x)); }

__device__ __forceinline__ void gload_lds16(const void* g, void* s) {
  __builtin_amdgcn_global_load_lds(
      (const __attribute__((address_space(1))) unsigned int*)g,
      (__attribute__((address_space(3))) unsigned int*)s, 16, 0, 0);
}

// ---------------- bf16 MFMA GEMM ----------------
// C = alpha * (A_hi [+ A_lo]) @ (B_hi [+ B_lo])^T + bias [+Cacc] [relu]
// MFMA stream order fixed: A_hi*B_hi [+ A_hi*B_lo if BPAIR] [+ A_lo*B_hi if DUAL].
// PIPE: 2-phase double-buffered K-loop (prefetch next tile under current MFMA).
// MODE 0: f32 out (+bias)   MODE 3: bf16 out   MODE 4: pair+relu+bias
// MODE 5: f32+bias+accum    MODE 6: decoder region-select
// MODE 7: bf16+bias+VT scatter (incl. K-pad zero fill)
template <int MODE, bool DUAL, bool BPAIR, bool BF32, bool PIPE>
__global__ __launch_bounds__(256) void bgemm_k(
    const bf16* __restrict__ A, const bf16* __restrict__ Alo,
    const bf16* __restrict__ Bh_, const bf16* __restrict__ Bl_,
    const float* __restrict__ Bf0, const float* __restrict__ Bf1,
    const float* __restrict__ Bf2,
    void* __restrict__ Cp, bf16* __restrict__ Clo, const float* __restrict__ Cacc,
    const float* __restrict__ bias, const float* __restrict__ bias1,
    const float* __restrict__ bias2, bf16* __restrict__ VTout, int mpad,
    int M, int N, int K, int lda, int ldb, int ldc, float alpha,
    long long sA1, long long sA2, long long sB1, long long sB2,
    long long sC1, long long sC2, int nh) {
  const int bz = blockIdx.z;
  const int b1 = bz / nh, b2 = bz - b1 * nh;
  A += (long long)b1 * sA1 + (long long)b2 * sA2;
  if (DUAL) Alo += (long long)b1 * sA1 + (long long)b2 * sA2;
  if (!BF32) {
    Bh_ += (long long)b1 * sB1 + (long long)b2 * sB2;
    if (BPAIR) Bl_ += (long long)b1 * sB1 + (long long)b2 * sB2;
  }
  const long long coff = (long long)b1 * sC1 + (long long)b2 * sC2;
  const int bm = blockIdx.y * 128, bn = blockIdx.x * 128;

  constexpr int NSTG = PIPE ? 2 : 1;
  __shared__ bf16 As[NSTG][128 * 32];
  __shared__ bf16 Ls[DUAL ? NSTG : 1][DUAL ? 128 * 32 : 8];
  __shared__ bf16 Bh[NSTG][128 * 32];
  __shared__ bf16 Bl[BPAIR ? NSTG : 1][BPAIR ? 128 * 32 : 8];
  const int tid = threadIdx.x;
  const int l = tid & 63;
  const int wr = ((tid >> 7) & 1) * 64;
  const int wc = ((tid >> 6) & 1) * 64;
  f32x4 acc[4][4];
#pragma unroll
  for (int i = 0; i < 4; ++i)
#pragma unroll
    for (int j = 0; j < 4; ++j) acc[i][j] = (f32x4){0.f, 0.f, 0.f, 0.f};

  auto STAGE = [&](int st, int k0) {
#pragma unroll
    for (int r = 0; r < 2; ++r) {
      int idx = r * 256 + tid;
      int row = idx >> 2, cs = idx & 3;
      int cg = cs ^ (row & 3);
      int ra = bm + row; if (ra > M - 1) ra = M - 1;
      int rb = bn + row; if (rb > N - 1) rb = N - 1;
      gload_lds16(A + (long long)ra * lda + k0 + cg * 8, &As[st][idx * 8]);
      if (DUAL) gload_lds16(Alo + (long long)ra * lda + k0 + cg * 8, &Ls[st][idx * 8]);
      if (BF32) {
        const float* src;
        if (rb < 5000)      src = Bf0 + (long long)rb * ldb + k0 + cg * 8;
        else if (rb < 5300) src = Bf1 + (long long)(rb - 5000) * ldb + k0 + cg * 8;
        else                src = Bf2 + (long long)(rb - 5300) * ldb + k0 + cg * 8;
        float4 x = *reinterpret_cast<const float4*>(src);
        float4 y = *reinterpret_cast<const float4*>(src + 4);
        float w[8] = {x.x, x.y, x.z, x.w, y.x, y.y, y.z, y.w};
        bf16 hb_[8], lb_[8];
#pragma unroll
        for (int q = 0; q < 8; ++q) {
          bf16 hq = (bf16)w[q];
          hb_[q] = hq;
          lb_[q] = (bf16)(w[q] - (float)hq);
        }
        *reinterpret_cast<s16x8*>(&Bh[st][idx * 8]) = *reinterpret_cast<s16x8*>(hb_);
        if (BPAIR)
          *reinterpret_cast<s16x8*>(&Bl[st][idx * 8]) = *reinterpret_cast<s16x8*>(lb_);
      } else {
        gload_lds16(Bh_ + (long long)rb * ldb + k0 + cg * 8, &Bh[st][idx * 8]);
        if (BPAIR) gload_lds16(Bl_ + (long long)rb * ldb + k0 + cg * 8, &Bl[st][idx * 8]);
      }
    }
  };

  auto COMPUTE = [&](int st) {
    s16x8 af[4], al[4], bh4[4], bl4[4];
#pragma unroll
    for (int mi = 0; mi < 4; ++mi) {
      int row = wr + mi * 16 + (l & 15);
      int ch = ((l >> 4) ^ row) & 3;
      af[mi] = *reinterpret_cast<const s16x8*>(&As[st][row * 32 + ch * 8]);
      if (DUAL) al[mi] = *reinterpret_cast<const s16x8*>(&Ls[st][row * 32 + ch * 8]);
    }
#pragma unroll
    for (int ni = 0; ni < 4; ++ni) {
      int row = wc + ni * 16 + (l & 15);
      int ch = ((l >> 4) ^ row) & 3;
      bh4[ni] = *reinterpret_cast<const s16x8*>(&Bh[st][row * 32 + ch * 8]);
      if (BPAIR) bl4[ni] = *reinterpret_cast<const s16x8*>(&Bl[st][row * 32 + ch * 8]);
    }
#pragma unroll
    for (int mi = 0; mi < 4; ++mi)
#pragma unroll
      for (int ni = 0; ni < 4; ++ni) {
        acc[mi][ni] =
            __builtin_amdgcn_mfma_f32_16x16x32_bf16(af[mi], bh4[ni], acc[mi][ni], 0, 0, 0);
        if (BPAIR)
          acc[mi][ni] =
              __builtin_amdgcn_mfma_f32_16x16x32_bf16(af[mi], bl4[ni], acc[mi][ni], 0, 0, 0);
        if (DUAL)
          acc[mi][ni] =
              __builtin_amdgcn_mfma_f32_16x16x32_bf16(al[mi], bh4[ni], acc[mi][ni], 0, 0, 0);
      }
  };

  if (!PIPE) {
    for (int k0 = 0; k0 < K; k0 += 32) {
      STAGE(0, k0);
      __syncthreads();
      COMPUTE(0);
      __syncthreads();
    }
  } else {
    // 2-phase: prefetch next K-tile under current MFMA (T3 minimum recipe).
    STAGE(0, 0);
    asm volatile("s_waitcnt vmcnt(0)" ::: "memory");
    __builtin_amdgcn_s_barrier();
    int cur = 0;
    for (int k0 = 0; k0 < K; k0 += 32) {
      if (k0 + 32 < K) STAGE(cur ^ 1, k0 + 32);  // issue loads for next tile
      COMPUTE(cur);                               // MFMA on current tile
      asm volatile("s_waitcnt vmcnt(0)" ::: "memory");
      __builtin_amdgcn_sched_barrier(0);
      __builtin_amdgcn_s_barrier();               // next tile ready; cur readers done
      cur ^= 1;
    }
  }

  const int lc = l & 15, lr4 = (l >> 4) * 4;
#pragma unroll
  for (int mi = 0; mi < 4; ++mi) {
#pragma unroll
    for (int j = 0; j < 4; ++j) {
      int r = bm + wr + mi * 16 + lr4 + j;
      if (MODE != 7 && r >= M) continue;
#pragma unroll
      for (int ni = 0; ni < 4; ++ni) {
        int c = bn + wc + ni * 16 + lc;
        if (c >= N) continue;
        float v = alpha * acc[mi][ni][j];
        if (MODE == 6) {
          v += (c < 5000) ? bias[c] : (c < 5300) ? bias1[c - 5000] : bias2[c - 5300];
        } else if (bias) {
          v += bias[c];
        }
        long long idx = coff + (long long)r * ldc + c;
        if (MODE == 7) {
          if (c >= 1024 && r < 3 * mpad) {
            bf16 pv = (r < M) ? (bf16)v : (bf16)0.f;
            int r3 = r % 3, s = r / 3;
            int hh = (c - 1024) >> 8, n = (c - 1024) & 255;
            VTout[(long long)((r3 * 2 + hh) * 256 + n) * mpad + s] = pv;
          }
          if (r < M) ((bf16*)Cp)[idx] = (bf16)v;
        } else if (MODE == 5) {
          ((float*)Cp)[idx] = v + Cacc[idx];
        } else if (MODE == 0) {
          ((float*)Cp)[idx] = v;
        } else if (MODE == 3) {
          ((bf16*)Cp)[idx] = (bf16)v;
        } else if (MODE == 4) {
          v = fmaxf(v, 0.f);
          bf16 hv = (bf16)v;
          ((bf16*)Cp)[idx] = hv;
          Clo[idx] = (bf16)(v - (float)hv);
        } else {  // MODE 6: decoder region select (poi 5000 | cat 300 | coo 1024)
          float* o0 = (float*)Cp;
          if (c < 5000)      o0[(long long)r * 5000 + c] = v;
          else if (c < 5300) o0[29120000LL + (long long)r * 300 + (c - 5000)] = v;
          else               o0[30867200LL + (long long)r * 1024 + (c - 5300)] = v;
        }
      }
    }
  }
}

static void bgemm(hipStream_t st, int mode, bool dual, bool bpair,
                  const bf16* A, const bf16* Alo, const bf16* Bh, const bf16* Bl,
                  void* Cp, bf16* Clo, const float* Cacc,
                  const float* bias, const float* bias1, const float* bias2,
                  bf16* VTout, int mpad,
                  int M, int N, int K, int lda, int ldb, int ldc, float alpha,
                  int batches = 1, long long sA1 = 0, long long sA2 = 0,
                  long long sB1 = 0, long long sB2 = 0, long long sC1 = 0,
                  long long sC2 = 0, int nh = 1,
                  const float* Bf0 = nullptr, const float* Bf1 = nullptr,
                  const float* Bf2 = nullptr, bool bf32 = false) {
  dim3 g((N + 127) / 128, (M + 127) / 128, batches), b(256);
  long long nblocks = (long long)g.x * g.y * g.z;
  const bool pipe = (!bf32) && (mode != 6) && nblocks <= 1024;
#define BGL(MD_, DU_, BP_, BFF_, PP_)                                                    \
  bgemm_k<MD_, DU_, BP_, BFF_, PP_><<<g, b, 0, st>>>(                                    \
      A, Alo, Bh, Bl, Bf0, Bf1, Bf2, Cp, Clo, Cacc, bias, bias1, bias2, VTout, mpad,     \
      M, N, K, lda, ldb, ldc, alpha, sA1, sA2, sB1, sB2, sC1, sC2, nh)
#define BGL2(MD_, DU_, BP_)                                                              \
  do { if (pipe) BGL(MD_, DU_, BP_, false, true); else BGL(MD_, DU_, BP_, false, false); \
  } while (0)
  if (mode == 0 && !dual && bpair)        BGL2(0, false, true);
  else if (mode == 0 && dual && bpair)    BGL2(0, true, true);
  else if (mode == 0 && !dual && !bpair)  BGL2(0, false, false);
  else if (mode == 3)                     BGL2(3, false, false);
  else if (mode == 4)                     BGL2(4, true, true);
  else if (mode == 5)                     BGL2(5, true, true);
  else if (mode == 6 && !bf32)            BGL(6, false, false, false, false);
  else if (mode == 6 && bf32)             BGL(6, false, false, true, false);
  else                                    BGL2(7, true, true);
#undef BGL2
#undef BGL
}

// ---------------- fp32 -> (hi, lo) bf16 split, segmented; ptrs computed on host ------
struct SegArgs {
  const float* src[8];
  bf16* hi[8];
  bf16* lo[8];
  int start[9];  // prefix sums in 8-element units; trailing entries = total
};
__global__ __launch_bounds__(256) void split_k(SegArgs a, int total8) {
  for (int i = blockIdx.x * 256 + threadIdx.x; i < total8; i += gridDim.x * 256) {
    int s = 0;
    while (i >= a.start[s + 1]) ++s;
    long long off = (long long)(i - a.start[s]) * 8;
    const float4* p = reinterpret_cast<const float4*>(a.src[s] + off);
    float4 x = p[0], y = p[1];
    float w[8] = {x.x, x.y, x.z, x.w, y.x, y.y, y.z, y.w};
    bf16 hb[8], lb[8];
#pragma unroll
    for (int q = 0; q < 8; ++q) {
      bf16 hq = (bf16)w[q];
      hb[q] = hq;
      lb[q] = (bf16)(w[q] - (float)hq);
    }
    *reinterpret_cast<s16x8*>(a.hi[s] + off) = *reinterpret_cast<s16x8*>(hb);
    if (a.lo[s]) *reinterpret_cast<s16x8*>(a.lo[s] + off) = *reinterpret_cast<s16x8*>(lb);
  }
}

// ---------------- embedding gather + concat + time-pos + mask -> bf16 ----------------
__global__ __launch_bounds__(256) void embed_k(
    const int* __restrict__ uid, const int* __restrict__ pid, const int* __restrict__ cid,
    const int* __restrict__ gid, const int* __restrict__ tmid, const int* __restrict__ mask,
    const float* __restrict__ ue, const float* __restrict__ pe, const float* __restrict__ ce,
    const float* __restrict__ ge, const float* __restrict__ tp, bf16* __restrict__ xb) {
  int e = blockIdx.x * 256 + threadIdx.x;
  if (e >= NN * ED) return;
  int n = e / ED, j = e - n * ED;
  int mi = mask[n];
  float fm = (float)mi;
  float v;
  if (j < 128)      v = ue[(long long)(uid[n] * mi) * 128 + j];
  else if (j < 256) v = pe[(long long)(pid[n] * mi) * 128 + (j - 128)];
  else if (j < 288) v = ce[(long long)(cid[n] * mi) * 32 + (j - 256)];
  else              v = ge[(long long)(gid[n] * mi) * 64 + (j - 288)];
  v += 0.5f * tp[(long long)(tmid[n] * mi) * ED + j];
  xb[e] = (bf16)(v * fm);
}

// ---------------- forget gates + c_red (reads children's c directly) ----------------
__global__ __launch_bounds__(256) void fcred_k(
    const float* __restrict__ wxa, const float* __restrict__ ufh,
    const float* __restrict__ bf_, const float* __restrict__ c, float* __restrict__ cred,
    int m, int cbase, int tl, int woff) {
  int e = blockIdx.x * 256 + threadIdx.x;
  if (e >= m * 512) return;
  int r = e >> 9, d = e & 511;
  float w = wxa[(long long)(woff + r) * 512 + d] + bf_[d];
  int t = r / tl, p = r - t * tl;
  long long cb = (long long)(cbase + t * 3 * tl + 3 * p) * 512 + d;
  long long ub = (long long)r * 1536;
  float acc = 0.f;
#pragma unroll
  for (int k = 0; k < 3; ++k) {
    float f = sigmoidf_(w + ufh[ub + k * 512 + d]);
    acc += f * c[cb + (long long)k * 512];
  }
  cred[e] = acc;
}

// ---------------- iou -> (h,c); h pair + scatter into next level's mailbox ----------
__global__ __launch_bounds__(256) void combine_k(
    const float* __restrict__ iou, const float* __restrict__ cred, float* __restrict__ c,
    bf16* __restrict__ hhi, bf16* __restrict__ hlo, int off, int m, int tl3, int tlp,
    bf16* __restrict__ nxthi, bf16* __restrict__ nxtlo) {
  int e = blockIdx.x * 256 + threadIdx.x;
  if (e >= m * 512) return;
  int r = e >> 9, d = e & 511;
  long long b = (long long)r * 1536;
  float iv = iou[b + d], ov = iou[b + 512 + d], uv = iou[b + 1024 + d];
  float cr = cred ? cred[e] : 0.f;
  float cn = sigmoidf_(iv) * tanhf(uv) + cr;
  float hn = sigmoidf_(ov) * tanhf(cn);
  long long o = (long long)(off + r) * 512 + d;
  c[o] = cn;
  bf16 hv = (bf16)hn;
  bf16 lo = (bf16)(hn - (float)hv);
  hhi[o] = hv;
  hlo[o] = lo;
  if (nxthi) {
    int t = r / tl3, q = r - t * tl3;
    int qp = q / 3, slot = q - 3 * qp;
    long long dst = (long long)(t * tlp + qp) * 1536 + slot * 512 + d;
    nxthi[dst] = hv;
    nxtlo[dst] = lo;
  }
}

// ---------------- LayerNorm width 512: LN((ahi+alo) + b)*w + bias -> pair ----------
__global__ __launch_bounds__(256) void ln_k(
    const bf16* __restrict__ ahi, const bf16* __restrict__ alo, const float* __restrict__ b,
    const float* __restrict__ w, const float* __restrict__ bias,
    bf16* __restrict__ ohi, bf16* __restrict__ olo) {
  int r = blockIdx.x, t = threadIdx.x;
  long long base = (long long)r * 512;
  float v0 = (float)ahi[base + t] + (float)alo[base + t] + b[base + t];
  float v1 = (float)ahi[base + 256 + t] + (float)alo[base + 256 + t] + b[base + 256 + t];
  __shared__ float s1[256], s2[256];
  s1[t] = v0 + v1;
  s2[t] = v0 * v0 + v1 * v1;
  __syncthreads();
  for (int s = 128; s > 0; s >>= 1) {
    if (t < s) { s1[t] += s1[t + s]; s2[t] += s2[t + s]; }
    __syncthreads();
  }
  float mu = s1[0] * (1.f / 512.f);
  float var = s2[0] * (1.f / 512.f) - mu * mu;
  float rs = rsqrtf(var + 1e-5f);
  float o0 = (v0 - mu) * rs * w[t] + bias[t];
  float o1 = (v1 - mu) * rs * w[256 + t] + bias[256 + t];
  bf16 h0 = (bf16)o0, h1 = (bf16)o1;
  ohi[base + t] = h0;       olo[base + t] = (bf16)(o0 - (float)h0);
  ohi[base + 256 + t] = h1; olo[base + 256 + t] = (bf16)(o1 - (float)h1);
}

// ---------------- row softmax fp32 -> bf16 probs IN PLACE over SC ----------------
// Pb row r = (bf16*)sc + r*2m (within row r's own fp32 storage); pads [m,mpad)=0.
__global__ __launch_bounds__(256) void softmax_pb_k(float* __restrict__ sc, int m, int mpad) {
  long long r = blockIdx.x;
  float* row = sc + r * (long long)m;
  bf16* prow = (bf16*)sc + r * (long long)(2 * m);
  int t = threadIdx.x;
  __shared__ float sh[256];
  float mx = -3.4e38f;
  for (int j = t; j < m; j += 256) mx = fmaxf(mx, row[j]);
  sh[t] = mx;
  __syncthreads();
  for (int s = 128; s > 0; s >>= 1) {
    if (t < s) sh[t] = fmaxf(sh[t], sh[t + s]);
    __syncthreads();
  }
  mx = sh[0];
  __syncthreads();
  float ev[6];  // ceil(1296/256) = 6 max
  float sum = 0.f;
  int cnt = 0;
  for (int j = t; j < m; j += 256) {
    float e = expf(row[j] - mx);
    ev[cnt++] = e;
    sum += e;
  }
  sh[t] = sum;
  __syncthreads();
  for (int s = 128; s > 0; s >>= 1) {
    if (t < s) sh[t] += sh[t + s];
    __syncthreads();
  }
  float inv = 1.f / sh[0];
  cnt = 0;
  for (int j = t; j < m; j += 256) prow[j] = (bf16)(ev[cnt++] * inv);
  for (int j = m + t; j < mpad; j += 256) prow[j] = (bf16)0.f;
}

}  // namespace

extern "C" void kernel_launch(void* const* d_in, const int* in_sizes, int n_in,
                              void* d_out, int out_size, void* d_ws, size_t ws_size,
                              hipStream_t stream) {
  const int* uid  = (const int*)d_in[0];
  const int* pid  = (const int*)d_in[1];
  const int* cid  = (const int*)d_in[2];
  const int* gid  = (const int*)d_in[3];
  const int* tmid = (const int*)d_in[4];
  const int* mask = (const int*)d_in[5];
  const float* ue = (const float*)d_in[6];
  const float* pe = (const float*)d_in[7];
  const float* ce = (const float*)d_in[8];
  const float* ge = (const float*)d_in[9];
  const float* tp = (const float*)d_in[10];
  const float* b_iou = (const float*)d_in[13];
  const float* b_f = (const float*)d_in[16];
  const float* qkv_b = (const float*)d_in[18];
  const float* out_b = (const float*)d_in[20];
  const float* ln1_w = (const float*)d_in[21];
  const float* ln1_b = (const float*)d_in[22];
  const float* ff1_b = (const float*)d_in[24];
  const float* ff2_b = (const float*)d_in[26];
  const float* ln2_w = (const float*)d_in[27];
  const float* ln2_b = (const float*)d_in[28];
  const float* dpw = (const float*)d_in[29];
  const float* dpb = (const float*)d_in[30];
  const float* dcw = (const float*)d_in[31];
  const float* dcb = (const float*)d_in[32];
  const float* dgw = (const float*)d_in[33];
  const float* dgb = (const float*)d_in[34];

  // ---- d_ws: H pair bf16 [0, 11.9MB), Cc fp32 [11.9, 23.9MB),
  //      decoder hi pool [23.9, 30.3MB) IF ws_size permits ----
  float* ws = (float*)d_ws;
  bf16* Hhi = (bf16*)ws;
  bf16* Hlo = Hhi + 2981888LL;
  float* Cc = ws + 2981888LL;
  bf16* DhiW = (bf16*)(ws + 5963776LL);        // 3,237,888 el -> ends fl 7,582,720
  const bool wsfit = ws_size >= 30330880ULL;   // 7,582,720 * 4 B

  // ---- d_out map (fl offsets) ----
  float* ob = (float*)d_out;
  float* IOUa = ob;                            // [0, 8,945,664)
  float* WXa  = ob + 8945664LL;                // [.., 9,936,896)
  float* CRED = ob + 9936896LL;                // [.., 10,600,448)
  bf16* RAhi  = (bf16*)(ob + 10600448LL);      // 1,990,656 el
  bf16* RAlo  = RAhi + 1990656LL;
  bf16* RBhi  = (bf16*)(ob + 12591104LL);
  bf16* RBlo  = RBhi + 1990656LL;
  bf16* UP    = (bf16*)(ob + 14581760LL);      // U pool: 9,437,184 el
  bf16* TE    = (bf16*)(ob + 19300352LL);      // TE pool: 6,291,456 el
  float* TB   = ob + 22446080LL;               // transient, 14,384,896 fl

  // U pool
  bf16* Uihi = UP;                  // U_iou hi (2,359,296)
  bf16* Uilo = UP + 2359296LL;
  bf16* Ufhi = UP + 4718592LL;      // U_f hi
  bf16* Uflo = UP + 7077888LL;
  // TE pool
  bf16* qkvhi = TE;                 // 1,572,864 (2 layers)
  bf16* qkvlo = TE + 1572864LL;
  bf16* outhi = TE + 3145728LL;     // 524,288
  bf16* outlo = TE + 3670016LL;
  bf16* ff1hi = TE + 4194304LL;
  bf16* ff1lo = TE + 4718592LL;
  bf16* ff2hi = TE + 5242880LL;
  bf16* ff2lo = TE + 5767168LL;

  // TB layout during level loop:
  float* SC   = TB;                            // [0, 10,077,696) fp32; Pb aliased inside
  float* PQ   = TB + 10077696LL;               // [.., 13,063,680): UFH / QKVb / ATTOb
  bf16* VT    = (bf16*)(TB + 13063680LL);      // 2,015,232 el -> ends TB+14,071,296
  // early-phase aliases in TB (dead before SC first written at level-4 scores):
  bf16* Xb    = (bf16*)TB;                     // 2,050,048 el = 1,025,024 fl
  bf16* WP    = (bf16*)(TB + 1025024LL);       // W pool: 1,441,792 el
  bf16* Wihi  = WP;
  bf16* Wilo  = WP + 540672LL;
  bf16* Wfhi  = WP + 1081344LL;
  bf16* Wflo  = WP + 1261568LL;

  float* UFH  = PQ;
  bf16* QKVb  = (bf16*)PQ;
  bf16* ATTOb = (bf16*)PQ;
  float* XB   = TB;                            // fp32, after Pb dead
  bf16* XChi  = (bf16*)(TB + 1990656LL);
  bf16* XClo  = (bf16*)(TB + 2985984LL);

  // 0) split all level-loop weights into hi/lo pools; decoder hi into d_ws
  {
    SegArgs a{};
    const int n8[8] = {294912, 294912, 196608, 65536, 65536, 65536, 67584, 22528};
    a.src[0] = (const float*)d_in[12]; a.hi[0] = Uihi;  a.lo[0] = Uilo;   // U_iou
    a.src[1] = (const float*)d_in[15]; a.hi[1] = Ufhi;  a.lo[1] = Uflo;   // U_f
    a.src[2] = (const float*)d_in[17]; a.hi[2] = qkvhi; a.lo[2] = qkvlo;  // qkv_w
    a.src[3] = (const float*)d_in[19]; a.hi[3] = outhi; a.lo[3] = outlo;  // out_w
    a.src[4] = (const float*)d_in[23]; a.hi[4] = ff1hi; a.lo[4] = ff1lo;  // ff1_w
    a.src[5] = (const float*)d_in[25]; a.hi[5] = ff2hi; a.lo[5] = ff2lo;  // ff2_w
    a.src[6] = (const float*)d_in[11]; a.hi[6] = Wihi;  a.lo[6] = Wilo;   // W_iou
    a.src[7] = (const float*)d_in[14]; a.hi[7] = Wfhi;  a.lo[7] = Wflo;   // W_f
    a.start[0] = 0;
    for (int i = 0; i < 8; ++i) a.start[i + 1] = a.start[i] + n8[i];
    int total8 = a.start[8];
    int blocks = (total8 + 255) / 256; if (blocks > 4096) blocks = 4096;
    split_k<<<blocks, 256, 0, stream>>>(a, total8);
    if (wsfit) {
      SegArgs d{};
      const int dn8[3] = {320000, 19200, 65536};
      d.src[0] = dpw; d.hi[0] = DhiW;             d.lo[0] = nullptr;  // lo unused
      d.src[1] = dcw; d.hi[1] = DhiW + 2560000LL; d.lo[1] = nullptr;
      d.src[2] = dgw; d.hi[2] = DhiW + 2713600LL; d.lo[2] = nullptr;
      d.start[0] = 0;
      for (int i = 0; i < 3; ++i) d.start[i + 1] = d.start[i] + dn8[i];
      for (int i = 3; i < 8; ++i) d.start[i + 1] = d.start[3];
      int dt8 = d.start[3];
      int db = (dt8 + 255) / 256; if (db > 4096) db = 4096;
      split_k<<<db, 256, 0, stream>>>(d, dt8);
    }
  }

  // 1) embeddings
  embed_k<<<(NN * ED + 255) / 256, 256, 0, stream>>>(uid, pid, cid, gid, tmid, mask,
                                                     ue, pe, ce, ge, tp, Xb);

  // 2) hoisted projections: IOU_all (no bias), WX_all
  bgemm(stream, 0, false, true, Xb, nullptr, Wihi, Wilo, IOUa, nullptr, nullptr,
        nullptr, nullptr, nullptr, nullptr, 0, NN, 1536, 352, 352, 352, 1536, 1.f);
  bgemm(stream, 0, false, true, Xb + 3888LL * ED, nullptr, Wfhi, Wflo, WXa, nullptr,
        nullptr, nullptr, nullptr, nullptr, nullptr, 0, 1936, 512, 352, 352, 352, 512, 1.f);

  // 3) leaves: combine + scatter into level-4 mailbox RA
  combine_k<<<(3888 * 512 + 255) / 256, 256, 0, stream>>>(
      IOUa, nullptr, Cc, Hhi, Hlo, 0, 3888, 243, 81, RAhi, RAlo);

  static const int OFFL[6] = {5808, 5760, 5616, 5184, 3888, 0};
  int tl = 81;
  for (int l = 4; l >= 0; --l, tl /= 3) {
    int m = 16 * tl;
    int off = OFFL[l];
    int cbase = OFFL[l + 1];
    int T = 3 * m;
    int mpad = (m + 31) & ~31;

    bgemm(stream, 0, true, true, RAhi, RAlo, Ufhi, Uflo, UFH, nullptr, nullptr,
          nullptr, nullptr, nullptr, nullptr, 0, m, 1536, 1536, 1536, 1536, 1536, 1.f);
    fcred_k<<<(m * 512 + 255) / 256, 256, 0, stream>>>(WXa, UFH, b_f, Cc, CRED,
                                                       m, cbase, tl, off - 3888);

    bf16 *curhi = RAhi, *curlo = RAlo, *nxthi = RBhi, *nxtlo = RBlo;
    for (int i = 0; i < 2; ++i) {
      // qkv (+fused V^T scatter with zero-filled K-pad)
      bgemm(stream, 7, true, true, curhi, curlo, qkvhi + (long long)i * 786432,
            qkvlo + (long long)i * 786432, QKVb, nullptr, nullptr,
            qkv_b + i * 1536, nullptr, nullptr, VT, mpad,
            T, 1536, 512, 512, 512, 1536, 1.f);
      // scores = (1/16) Q@K^T
      bgemm(stream, 0, false, false, QKVb, nullptr, QKVb + 512, nullptr, SC, nullptr,
            nullptr, nullptr, nullptr, nullptr, nullptr, 0,
            m, m, 256, 4608, 4608, m, 0.0625f,
            6, 1536, 256, 1536, 256, 2LL * m * m, (long long)m * m, 2);
      softmax_pb_k<<<6 * m, 256, 0, stream>>>(SC, m, mpad);
      // attn @ V: Pb in-place over SC, lda = 2m, batch strides {4m^2, 2m^2}
      bgemm(stream, 3, false, false, (bf16*)SC, nullptr, VT, nullptr, ATTOb, nullptr,
            nullptr, nullptr, nullptr, nullptr, nullptr, 0,
            m, 256, mpad, 2 * m, mpad, 1536, 1.f,
            6, 4LL * m * m, 2LL * m * m, 2LL * 256 * mpad, 256LL * mpad, 512, 256, 2);
      bgemm(stream, 0, false, true, ATTOb, nullptr, outhi + (long long)i * 262144,
            outlo + (long long)i * 262144, XB, nullptr, nullptr,
            out_b + i * 512, nullptr, nullptr, nullptr, 0,
            T, 512, 512, 512, 512, 512, 1.f);
      ln_k<<<T, 256, 0, stream>>>(curhi, curlo, XB, ln1_w + i * 512, ln1_b + i * 512,
                                  nxthi, nxtlo);
      bgemm(stream, 4, true, true, nxthi, nxtlo, ff1hi + (long long)i * 262144,
            ff1lo + (long long)i * 262144, XChi, XClo, nullptr,
            ff1_b + i * 512, nullptr, nullptr, nullptr, 0,
            T, 512, 512, 512, 512, 512, 1.f);
      bgemm(stream, 0, true, true, XChi, XClo, ff2hi + (long long)i * 262144,
            ff2lo + (long long)i * 262144, XB, nullptr, nullptr,
            ff2_b + i * 512, nullptr, nullptr, nullptr, 0,
            T, 512, 512, 512, 512, 512, 1.f);
      ln_k<<<T, 256, 0, stream>>>(nxthi, nxtlo, XB, ln2_w + i * 512, ln2_b + i * 512,
                                  curhi, curlo);
    }

    // iou: in-place accumulate into IOU_all rows [off, off+m) with b_iou
    bgemm(stream, 5, true, true, curhi, curlo, Uihi, Uilo,
          IOUa + (long long)off * 1536, nullptr, IOUa + (long long)off * 1536,
          b_iou, nullptr, nullptr, nullptr, 0, m, 1536, 1536, 1536, 1536, 1536, 1.f);
    combine_k<<<(m * 512 + 255) / 256, 256, 0, stream>>>(
        IOUa + (long long)off * 1536, CRED, Cc, Hhi, Hlo, off, m, tl, tl / 3,
        l > 0 ? RAhi : nullptr, l > 0 ? RAlo : nullptr);
  }

  // 4) merged decoders: single-stream hi*hi (final op; error bounded ~3e-3)
  if (wsfit) {
    bgemm(stream, 6, false, false, Hhi, nullptr, DhiW, nullptr, ob, nullptr, nullptr,
          dpb, dcb, dgb, nullptr, 0, NN, 6324, 512, 512, 512, 0, 1.f);
  } else {
    bgemm(stream, 6, false, false, Hhi, nullptr, nullptr, nullptr, ob, nullptr, nullptr,
          dpb, dcb, dgb, nullptr, 0, NN, 6324, 512, 512, 512, 0, 1.f,
          1, 0, 0, 0, 0, 0, 0, 1, dpw, dcw, dgw, true);
  }
}